// Round 6
// baseline (1328.425 us; speedup 1.0000x reference)
//
#include <hip/hip_runtime.h>
#include <math.h>

#define LSEQ 1024
#define DMODEL 768
#define NHEAD 8
#define HDIM 96
#define DI_ 1536
#define NST 16
#define DTR_ 48
#define FF_ 3072

typedef __attribute__((ext_vector_type(8))) short short8;
typedef __attribute__((ext_vector_type(4))) short short4_t;
typedef __attribute__((ext_vector_type(4))) float f32x4;

__device__ inline short f2bf(float f) {
  unsigned u = __builtin_bit_cast(unsigned, f);
  unsigned r = u + 0x7FFFu + ((u >> 16) & 1u);   // round-to-nearest-even
  return (short)(r >> 16);
}

// ---------------------------------------------------------------------------
// 128xBN bf16 MFMA GEMM. C[m,n] = act(A[m,:].W[n,:] + bias[n]) (+res / *=C)
// Requires: M=2048, Ncols % BN == 0, Kd % 32 == 0. BK=32, 4 waves.
// BN=128: wave = 64x64 quadrant (16 MFMA/K-step). BN=64: wave = 32x64.
// Grouped block order (GROUP_M=4) keeps an A-panel + W-slice L2-resident.
// ---------------------------------------------------------------------------
template<int BN>
__global__ __launch_bounds__(256) void gemm_bf16_big(
    const float* __restrict__ A, int lda, int flipA,
    const float* __restrict__ W,
    const float* __restrict__ bias,
    const float* __restrict__ residual,
    float* __restrict__ C, int ldc, int colOff, int flipC,
    int Ncols, int Kd, int act, int mulC)
{
  constexpr int WSLAB = BN / 32;
  constexpr int MI = (BN == 128) ? 4 : 2;     // A-frags per wave
  constexpr int NI = 4;                       // B-frags per wave
  constexpr int WRS = (BN == 128) ? 64 : 32;  // rows per wave

  __shared__ short As[128][40];
  __shared__ short Ws[BN][40];

  const int ncl = Ncols / BN;
  const int ppg = 4 * ncl;                    // blocks per 4-row-tile group
  const int rm = (blockIdx.x / ppg) * 4 + (blockIdx.x % ppg) % 4;
  const int cn = (blockIdx.x % ppg) / 4;
  const int row0 = rm * 128, col0 = cn * BN;

  const int tid = threadIdx.x;
  const int w = tid >> 6, lane = tid & 63;
  const int m16 = lane & 15, kg = lane >> 4;
  const int wr = (BN == 128) ? (w >> 1) : w;
  const int wc = (BN == 128) ? (w & 1) : 0;

  f32x4 acc[MI][NI] = {};

  const int r8 = tid >> 3;          // 0..31
  const int kk = (tid & 7) << 2;    // 0..28
  const float* aptr[4];
  #pragma unroll
  for (int u = 0; u < 4; ++u) {
    int gm = row0 + u * 32 + r8;
    int bb = gm >> 10, ll = gm & 1023;
    if (flipA) ll = 1023 - ll;
    aptr[u] = A + (size_t)(bb * LSEQ + ll) * lda + kk;
  }
  const float* wptr[WSLAB];
  #pragma unroll
  for (int u = 0; u < WSLAB; ++u)
    wptr[u] = W + (size_t)(col0 + u * 32 + r8) * Kd + kk;

  for (int k0 = 0; k0 < Kd; k0 += 32) {
    __syncthreads();
    #pragma unroll
    for (int u = 0; u < 4; ++u) {
      float4 av = *(const float4*)(aptr[u] + k0);
      *(short4_t*)&As[u * 32 + r8][kk] =
          short4_t{f2bf(av.x), f2bf(av.y), f2bf(av.z), f2bf(av.w)};
    }
    #pragma unroll
    for (int u = 0; u < WSLAB; ++u) {
      float4 wv = *(const float4*)(wptr[u] + k0);
      *(short4_t*)&Ws[u * 32 + r8][kk] =
          short4_t{f2bf(wv.x), f2bf(wv.y), f2bf(wv.z), f2bf(wv.w)};
    }
    __syncthreads();
    short8 a[MI], b[NI];
    #pragma unroll
    for (int mi = 0; mi < MI; ++mi)
      a[mi] = *(const short8*)&As[wr * WRS + mi * 16 + m16][kg << 3];
    #pragma unroll
    for (int ni = 0; ni < NI; ++ni)
      b[ni] = *(const short8*)&Ws[wc * 64 + ni * 16 + m16][kg << 3];
    #pragma unroll
    for (int mi = 0; mi < MI; ++mi)
      #pragma unroll
      for (int ni = 0; ni < NI; ++ni)
        acc[mi][ni] = __builtin_amdgcn_mfma_f32_16x16x32_bf16(a[mi], b[ni],
                                                              acc[mi][ni], 0, 0, 0);
  }

  #pragma unroll
  for (int ni = 0; ni < NI; ++ni) {
    int gn = col0 + wc * 64 + ni * 16 + m16;
    float bv = bias ? bias[gn] : 0.f;
    #pragma unroll
    for (int mi = 0; mi < MI; ++mi) {
      #pragma unroll
      for (int r = 0; r < 4; ++r) {
        int gm = row0 + wr * WRS + mi * 16 + (kg << 2) + r;
        int bb = gm >> 10, ll = gm & 1023;
        if (flipC) ll = 1023 - ll;
        float v = acc[mi][ni][r] + bv;
        if (act == 1) v = fmaxf(v, 0.f) + log1pf(__expf(-fabsf(v)));   // softplus
        else if (act == 2) v = v / (1.f + __expf(-v));                 // silu
        size_t idx = (size_t)(bb * LSEQ + ll) * ldc + colOff + gn;
        if (mulC) C[idx] *= v;
        else if (residual) C[idx] = residual[idx] + v;
        else C[idx] = v;
      }
    }
  }
}

// ---------------------------------------------------------------------------
// fp32 GEMM (kept for the dt projection: K=48)
// ---------------------------------------------------------------------------
__global__ __launch_bounds__(256) void gemm_f32(
    const float* __restrict__ A, int lda, int flipA,
    const float* __restrict__ W,
    const float* __restrict__ bias,
    const float* __restrict__ residual,
    float* __restrict__ C, int ldc, int colOff, int flipC,
    int Ncols, int Kd, int act, int mulC)
{
  __shared__ float As[16][65];
  __shared__ float Bs[16][65];
  const int row0 = blockIdx.y * 64, col0 = blockIdx.x * 64;
  const int tid = threadIdx.x;
  const int tx = tid & 15, ty = tid >> 4;
  float acc[4][4] = {};
  const int lm = tid >> 2;
  const int lk = (tid & 3) << 2;
  int gmL = row0 + lm;
  int bbL = gmL >> 10, llL = gmL & 1023;
  if (flipA) llL = LSEQ - 1 - llL;
  const float* arow = A + (size_t)(bbL * LSEQ + llL) * lda;
  int gnL = col0 + lm;
  const bool wvalid = (gnL < Ncols);
  const float* wrow = W + (size_t)(wvalid ? gnL : 0) * Kd;

  for (int k0 = 0; k0 < Kd; k0 += 16) {
    #pragma unroll
    for (int u = 0; u < 4; ++u) {
      int kkk = k0 + lk + u;
      bool kin = (kkk < Kd);
      As[lk + u][lm] = kin ? arow[kkk] : 0.f;
      Bs[lk + u][lm] = (kin && wvalid) ? wrow[kkk] : 0.f;
    }
    __syncthreads();
    #pragma unroll
    for (int kkk = 0; kkk < 16; ++kkk) {
      float a[4], bv[4];
      #pragma unroll
      for (int i = 0; i < 4; ++i) a[i] = As[kkk][(ty << 2) + i];
      #pragma unroll
      for (int j = 0; j < 4; ++j) bv[j] = Bs[kkk][(tx << 2) + j];
      #pragma unroll
      for (int i = 0; i < 4; ++i)
        #pragma unroll
        for (int j = 0; j < 4; ++j)
          acc[i][j] = fmaf(a[i], bv[j], acc[i][j]);
    }
    __syncthreads();
  }

  #pragma unroll
  for (int i = 0; i < 4; ++i) {
    int gm = row0 + (ty << 2) + i;
    int bb = gm >> 10, ll = gm & 1023;
    if (flipC) ll = LSEQ - 1 - ll;
    size_t base = (size_t)(bb * LSEQ + ll) * ldc + colOff;
    #pragma unroll
    for (int j = 0; j < 4; ++j) {
      int gn = col0 + (tx << 2) + j;
      if (gn >= Ncols) continue;
      float v = acc[i][j];
      if (bias) v += bias[gn];
      if (act == 1) v = fmaxf(v, 0.f) + log1pf(__expf(-fabsf(v)));
      else if (act == 2) v = v / (1.f + __expf(-v));
      size_t idx = base + gn;
      if (mulC) C[idx] *= v;
      else if (residual) C[idx] = residual[idx] + v;
      else C[idx] = v;
    }
  }
}

// ---------------------------------------------------------------------------
// Split-K fp32 GEMM for the skinny xp projection (M=2048, N=80, K=1536).
// ---------------------------------------------------------------------------
#define XP_KSPLIT 8
#define XP_KCH 192
__global__ __launch_bounds__(256) void xp_part(
    const float* __restrict__ A,            // XC 2048x1536
    const float* __restrict__ W,            // 80x1536
    float* __restrict__ PART)
{
  __shared__ float As[64][34];
  __shared__ float Ws[80][34];
  const int tid = threadIdx.x;
  const int row0 = blockIdx.x * 64;
  const int kbase = blockIdx.y * XP_KCH;
  const int ty = tid >> 4, tx = tid & 15;

  float acc[4][5] = {};

  for (int ch = 0; ch < XP_KCH; ch += 32) {
    const int gk = kbase + ch;
    __syncthreads();
    #pragma unroll
    for (int u = 0; u < 2; ++u) {
      int i = tid + u * 256;
      int r = i >> 3, k4 = (i & 7) << 2;
      *(float4*)&As[r][k4] = *(const float4*)&A[(size_t)(row0 + r) * 1536 + gk + k4];
    }
    #pragma unroll
    for (int u = 0; u < 3; ++u) {
      int j = tid + u * 256;
      if (j < 640) {
        int c = j >> 3, k4 = (j & 7) << 2;
        *(float4*)&Ws[c][k4] = *(const float4*)&W[(size_t)c * 1536 + gk + k4];
      }
    }
    __syncthreads();
    #pragma unroll
    for (int k = 0; k < 32; k += 2) {
      float2 a2[4], w2[5];
      #pragma unroll
      for (int i = 0; i < 4; ++i) a2[i] = *(const float2*)&As[ty + 16 * i][k];
      #pragma unroll
      for (int j = 0; j < 5; ++j) w2[j] = *(const float2*)&Ws[tx + 16 * j][k];
      #pragma unroll
      for (int i = 0; i < 4; ++i)
        #pragma unroll
        for (int j = 0; j < 5; ++j) {
          acc[i][j] = fmaf(a2[i].x, w2[j].x, acc[i][j]);
          acc[i][j] = fmaf(a2[i].y, w2[j].y, acc[i][j]);
        }
    }
  }

  float* pbase = PART + (size_t)blockIdx.y * 2048 * 80;
  #pragma unroll
  for (int i = 0; i < 4; ++i) {
    int gr = row0 + ty + 16 * i;
    #pragma unroll
    for (int j = 0; j < 5; ++j)
      pbase[(size_t)gr * 80 + tx + 16 * j] = acc[i][j];
  }
}

__global__ __launch_bounds__(256) void xp_reduce(
    const float* __restrict__ PART, float* __restrict__ DBC)
{
  int t = blockIdx.x * 256 + threadIdx.x;
  float s = 0.f;
  #pragma unroll
  for (int ks = 0; ks < XP_KSPLIT; ++ks)
    s += PART[(size_t)ks * 2048 * 80 + t];
  DBC[t] = s;
}

// ---------------------------------------------------------------------------
// MFMA flash attention. One block = one (b,h) x 64 q rows; 4 waves x 16 rows.
// ---------------------------------------------------------------------------
__global__ __launch_bounds__(256) void attn_mfma(const float* __restrict__ qkv,
                                                 float* __restrict__ o)
{
  __shared__ short Ks[64][104];
  __shared__ short Vt[96][72];
  __shared__ short Ps[4][16][72];

  const int bh = blockIdx.y;
  const int b_ = bh >> 3, h = bh & 7;
  const int q0 = blockIdx.x * 64;
  const int tid = threadIdx.x;
  const int w = tid >> 6, lane = tid & 63;
  const int m16 = lane & 15, g4 = lane >> 4;

  const float sc2 = 0.10206207261596577f * 1.4426950408889634f;

  short8 qf[3];
  {
    const float* qrow = qkv + ((size_t)(b_ * LSEQ) + q0 + w * 16 + m16) * 2304 + h * HDIM;
    #pragma unroll
    for (int c = 0; c < 3; ++c) {
      float4 v0 = *(const float4*)(qrow + c * 32 + g4 * 8);
      float4 v1 = *(const float4*)(qrow + c * 32 + g4 * 8 + 4);
      qf[c] = short8{f2bf(v0.x), f2bf(v0.y), f2bf(v0.z), f2bf(v0.w),
                     f2bf(v1.x), f2bf(v1.y), f2bf(v1.z), f2bf(v1.w)};
    }
  }

  float m_run[4], l_run[4];
  #pragma unroll
  for (int r = 0; r < 4; ++r) { m_run[r] = -INFINITY; l_run[r] = 0.f; }
  f32x4 oacc[6];
  #pragma unroll
  for (int ct = 0; ct < 6; ++ct) oacc[ct] = (f32x4)(0.f);

  const int kr = tid >> 2;
  const int cc = (tid & 3) * 24;

  for (int t = 0; t < LSEQ / 64; ++t) {
    const int k0 = t * 64;
    __syncthreads();
    {
      const float* kp = qkv + ((size_t)(b_ * LSEQ) + k0 + kr) * 2304 + DMODEL + h * HDIM + cc;
      const float* vp = kp + DMODEL;
      #pragma unroll
      for (int u = 0; u < 6; ++u) {
        float4 kv = *(const float4*)(kp + u * 4);
        *(short4_t*)&Ks[kr][cc + u * 4] =
            short4_t{f2bf(kv.x), f2bf(kv.y), f2bf(kv.z), f2bf(kv.w)};
        float4 vv = *(const float4*)(vp + u * 4);
        Vt[cc + u * 4 + 0][kr] = f2bf(vv.x);
        Vt[cc + u * 4 + 1][kr] = f2bf(vv.y);
        Vt[cc + u * 4 + 2][kr] = f2bf(vv.z);
        Vt[cc + u * 4 + 3][kr] = f2bf(vv.w);
      }
    }
    __syncthreads();

    f32x4 sacc[4];
    #pragma unroll
    for (int kt = 0; kt < 4; ++kt) sacc[kt] = (f32x4)(0.f);
    #pragma unroll
    for (int c = 0; c < 3; ++c) {
      #pragma unroll
      for (int kt = 0; kt < 4; ++kt) {
        short8 bfrag = *(const short8*)&Ks[kt * 16 + m16][c * 32 + g4 * 8];
        sacc[kt] = __builtin_amdgcn_mfma_f32_16x16x32_bf16(qf[c], bfrag, sacc[kt], 0, 0, 0);
      }
    }

    #pragma unroll
    for (int r = 0; r < 4; ++r) {
      float s0 = sacc[0][r] * sc2, s1 = sacc[1][r] * sc2;
      float s2v = sacc[2][r] * sc2, s3 = sacc[3][r] * sc2;
      float mv = fmaxf(fmaxf(s0, s1), fmaxf(s2v, s3));
      mv = fmaxf(mv, __shfl_xor(mv, 1));
      mv = fmaxf(mv, __shfl_xor(mv, 2));
      mv = fmaxf(mv, __shfl_xor(mv, 4));
      mv = fmaxf(mv, __shfl_xor(mv, 8));
      float mnew = fmaxf(m_run[r], mv);
      float scale = exp2f(m_run[r] - mnew);
      float p0 = exp2f(s0 - mnew), p1 = exp2f(s1 - mnew);
      float p2 = exp2f(s2v - mnew), p3 = exp2f(s3 - mnew);
      short* pr = &Ps[w][g4 * 4 + r][m16];
      pr[0]  = f2bf(p0);
      pr[16] = f2bf(p1);
      pr[32] = f2bf(p2);
      pr[48] = f2bf(p3);
      float ps = p0 + p1 + p2 + p3;
      ps += __shfl_xor(ps, 1);
      ps += __shfl_xor(ps, 2);
      ps += __shfl_xor(ps, 4);
      ps += __shfl_xor(ps, 8);
      l_run[r] = l_run[r] * scale + ps;
      m_run[r] = mnew;
      #pragma unroll
      for (int ct = 0; ct < 6; ++ct) oacc[ct][r] *= scale;
    }

    #pragma unroll
    for (int kc = 0; kc < 2; ++kc) {
      short8 pa = *(const short8*)&Ps[w][m16][kc * 32 + g4 * 8];
      #pragma unroll
      for (int ct = 0; ct < 6; ++ct) {
        short8 vb = *(const short8*)&Vt[ct * 16 + m16][kc * 32 + g4 * 8];
        oacc[ct] = __builtin_amdgcn_mfma_f32_16x16x32_bf16(pa, vb, oacc[ct], 0, 0, 0);
      }
    }
  }

  #pragma unroll
  for (int r = 0; r < 4; ++r) {
    float inv = 1.f / l_run[r];
    float* orow = o + ((size_t)(b_ * LSEQ) + q0 + w * 16 + g4 * 4 + r) * DMODEL + h * HDIM;
    #pragma unroll
    for (int ct = 0; ct < 6; ++ct)
      orow[ct * 16 + m16] = oacc[ct][r] * inv;
  }
}

// ---------------------------------------------------------------------------
// GLCE convs (kernels 3/5/7, 3 in-ch per out-ch, exact gelu)
// ---------------------------------------------------------------------------
__global__ __launch_bounds__(256) void glce_conv(
    const float* __restrict__ x,
    const float* __restrict__ w3, const float* __restrict__ b3,
    const float* __restrict__ w5, const float* __restrict__ b5,
    const float* __restrict__ w7, const float* __restrict__ b7,
    float* __restrict__ loc)
{
  int idx = blockIdx.x * 256 + threadIdx.x;
  int c = idx % DMODEL;
  int bl = idx / DMODEL;
  int l = bl & 1023, b_ = bl >> 10;
  int cs = c >> 8, ch = c & 255;
  const float* wp; float bias; int kt, pad;
  if (cs == 0)      { wp = w3 + ch * 9;  bias = b3[ch]; kt = 3; pad = 1; }
  else if (cs == 1) { wp = w5 + ch * 15; bias = b5[ch]; kt = 5; pad = 2; }
  else              { wp = w7 + ch * 21; bias = b7[ch]; kt = 7; pad = 3; }
  float acc = bias;
  const float* xb = x + (size_t)(b_ * LSEQ) * DMODEL;
  for (int i = 0; i < 3; ++i) {
    int d = 3 * ch + i;
    for (int t = 0; t < kt; ++t) {
      int ls = l - pad + t;
      if (ls >= 0 && ls < LSEQ)
        acc = fmaf(xb[(size_t)ls * DMODEL + d], wp[i * kt + t], acc);
    }
  }
  loc[idx] = 0.5f * acc * (1.f + erff(acc * 0.7071067811865475f));
}

// ---------------------------------------------------------------------------
// Mamba depthwise causal conv (K=4) + silu
// ---------------------------------------------------------------------------
__global__ __launch_bounds__(256) void mamba_conv_f32(
    const float* __restrict__ xiz, const float* __restrict__ cw,
    const float* __restrict__ cb, float* __restrict__ xc)
{
  int idx = blockIdx.x * 256 + threadIdx.x;
  int d = idx % DI_;
  int bl = idx / DI_;
  int l = bl & 1023, b_ = bl >> 10;
  const float* w = cw + d * 4;
  float acc = cb[d];
  #pragma unroll
  for (int t = 0; t < 4; ++t) {
    int ls = l - 3 + t;
    if (ls >= 0)
      acc = fmaf(xiz[((size_t)(b_ * LSEQ + ls)) * 3072 + d], w[t], acc);
  }
  xc[idx] = acc / (1.f + __expf(-acc));
}

// ---------------------------------------------------------------------------
// Chunked selective scan. CHUNK=64, NCHUNK=16.
// ---------------------------------------------------------------------------
__global__ __launch_bounds__(256) void mamba_scan_part(
    const float* __restrict__ dbc, const float* __restrict__ delta,
    const float* __restrict__ xc, const float* __restrict__ A_log,
    float* __restrict__ SS, float* __restrict__ PP)
{
  const int bc = blockIdx.x;
  const int b_ = bc / (96 * 16);
  const int rem = bc % (96 * 16);
  const int d0 = (rem >> 4) << 4;
  const int ck = rem & 15;
  const int tid = threadIdx.x;
  const int dl = tid >> 4, n = tid & 15;
  const int d = d0 + dl;
  const float a2 = -__expf(A_log[d * 16 + n]) * 1.4426950408889634f;

  __shared__ float sdel[64][16];
  __shared__ float sxc[64][16];
  __shared__ float sB[64][16];
  const size_t rowb = (size_t)b_ * LSEQ + ck * 64;

  #pragma unroll
  for (int k = 0; k < 4; ++k) {
    int i = tid + k * 256;
    int lc = i >> 4, c = i & 15;
    size_t row = rowb + lc;
    sdel[lc][c] = delta[row * 1536 + d0 + c];
    sxc[lc][c]  = xc[row * 1536 + d0 + c];
    sB[lc][c]   = dbc[row * 80 + 48 + c];
  }
  __syncthreads();

  float h = 0.f, sumd = 0.f;
  for (int lc = 0; lc < 64; ++lc) {
    float dlv = sdel[lc][dl];
    float xv  = sxc[lc][dl];
    float dA = exp2f(dlv * a2);
    h = fmaf(dA, h, dlv * xv * sB[lc][n]);
    sumd += dlv;
  }
  size_t idx = (((size_t)b_ * 1536 + d) * 16 + ck) * 16 + n;
  SS[idx] = h;
  PP[idx] = exp2f(a2 * sumd);
}

__global__ __launch_bounds__(256) void mamba_scan_comb(
    const float* __restrict__ SS, const float* __restrict__ PP,
    float* __restrict__ HI)
{
  int t = blockIdx.x * 256 + threadIdx.x;
  size_t base = (size_t)(t >> 4) * 256 + (t & 15);
  float run = 0.f;
  #pragma unroll
  for (int c = 0; c < 16; ++c) {
    size_t idx = base + c * 16;
    HI[idx] = run;
    run = fmaf(PP[idx], run, SS[idx]);
  }
}

__global__ __launch_bounds__(256) void mamba_scan_fin(
    const float* __restrict__ dbc, const float* __restrict__ delta,
    const float* __restrict__ xc, const float* __restrict__ xiz,
    const float* __restrict__ A_log, const float* __restrict__ Dp,
    const float* __restrict__ HI, float* __restrict__ yg)
{
  const int bc = blockIdx.x;
  const int b_ = bc / (96 * 16);
  const int rem = bc % (96 * 16);
  const int d0 = (rem >> 4) << 4;
  const int ck = rem & 15;
  const int tid = threadIdx.x;
  const int dl = tid >> 4, n = tid & 15;
  const int d = d0 + dl;
  const float a2 = -__expf(A_log[d * 16 + n]) * 1.4426950408889634f;
  const float dv = Dp[d];

  __shared__ float sdel[64][16];
  __shared__ float sxc[64][16];
  __shared__ float sz[64][16];
  __shared__ float sB[64][16];
  __shared__ float sC[64][16];
  __shared__ float sy[64][16];
  const size_t rowb = (size_t)b_ * LSEQ + ck * 64;

  #pragma unroll
  for (int k = 0; k < 4; ++k) {
    int i = tid + k * 256;
    int lc = i >> 4, c = i & 15;
    size_t row = rowb + lc;
    sdel[lc][c] = delta[row * 1536 + d0 + c];
    sxc[lc][c]  = xc[row * 1536 + d0 + c];
    sz[lc][c]   = xiz[row * 3072 + 1536 + d0 + c];
    sB[lc][c]   = dbc[row * 80 + 48 + c];
    sC[lc][c]   = dbc[row * 80 + 64 + c];
  }
  __syncthreads();

  float h = HI[(((size_t)b_ * 1536 + d) * 16 + ck) * 16 + n];
  for (int lc = 0; lc < 64; ++lc) {
    float dlv = sdel[lc][dl];
    float xv  = sxc[lc][dl];
    float dA = exp2f(dlv * a2);
    h = fmaf(dA, h, dlv * xv * sB[lc][n]);
    float p = h * sC[lc][n];
    p += __shfl_xor(p, 1);
    p += __shfl_xor(p, 2);
    p += __shfl_xor(p, 4);
    p += __shfl_xor(p, 8);
    if (n == 0) {
      float zv = sz[lc][dl];
      float y = p + xv * dv;
      sy[lc][dl] = y * (zv / (1.f + __expf(-zv)));
    }
  }
  __syncthreads();
  #pragma unroll
  for (int k = 0; k < 4; ++k) {
    int i = tid + k * 256;
    int lc = i >> 4, c = i & 15;
    yg[(rowb + lc) * 1536 + d0 + c] = sy[lc][c];
  }
}

// ---------------------------------------------------------------------------
// LayerNorm over last dim (768)
// ---------------------------------------------------------------------------
__global__ __launch_bounds__(256) void ln_f32(
    const float* __restrict__ in, const float* __restrict__ g,
    const float* __restrict__ b, float* __restrict__ out)
{
  int row = blockIdx.x * 4 + (threadIdx.x >> 6);
  int lane = threadIdx.x & 63;
  const float* xr = in + (size_t)row * DMODEL;
  float v[12];
  float s = 0.f, s2 = 0.f;
  #pragma unroll
  for (int i = 0; i < 12; ++i) {
    float t = xr[i * 64 + lane];
    v[i] = t; s += t; s2 = fmaf(t, t, s2);
  }
  #pragma unroll
  for (int off = 1; off < 64; off <<= 1) {
    s += __shfl_xor(s, off);
    s2 += __shfl_xor(s2, off);
  }
  float mean = s * (1.f / 768.f);
  float var = s2 * (1.f / 768.f) - mean * mean;
  float inv = rsqrtf(var + 1e-5f);
  float* orow = out + (size_t)row * DMODEL;
  #pragma unroll
  for (int i = 0; i < 12; ++i) {
    int c = i * 64 + lane;
    orow[c] = (v[i] - mean) * inv * g[c] + b[c];
  }
}

__global__ __launch_bounds__(256) void add3_f32(
    const float* __restrict__ a, const float* __restrict__ b,
    const float* __restrict__ c, float* __restrict__ o)
{
  int i = blockIdx.x * 256 + threadIdx.x;
  o[i] = a[i] + b[i] + c[i];
}

// ---------------------------------------------------------------------------
extern "C" void kernel_launch(void* const* d_in, const int* in_sizes, int n_in,
                              void* d_out, int out_size, void* d_ws, size_t ws_size,
                              hipStream_t stream)
{
  (void)in_sizes; (void)n_in; (void)out_size; (void)ws_size;
  const float* x         = (const float*)d_in[0];
  const float* qkv_w     = (const float*)d_in[1];
  const float* qkv_b     = (const float*)d_in[2];
  const float* att_out_w = (const float*)d_in[3];
  const float* att_out_b = (const float*)d_in[4];
  const float* conv3_w   = (const float*)d_in[5];
  const float* conv3_b   = (const float*)d_in[6];
  const float* conv5_w   = (const float*)d_in[7];
  const float* conv5_b   = (const float*)d_in[8];
  const float* conv7_w   = (const float*)d_in[9];
  const float* conv7_b   = (const float*)d_in[10];
  const float* gproj_w   = (const float*)d_in[11];
  const float* gproj_b   = (const float*)d_in[12];
  const float* lproj_w   = (const float*)d_in[13];
  const float* lproj_b   = (const float*)d_in[14];
  const float* fus_w     = (const float*)d_in[15];
  const float* fus_b     = (const float*)d_in[16];
  const float* glce_g    = (const float*)d_in[17];
  const float* glce_bb   = (const float*)d_in[18];
  const float* ssm_g     = (const float*)d_in[19];
  const float* ssm_bb    = (const float*)d_in[20];
  const float* in_w[2]   = {(const float*)d_in[21], (const float*)d_in[30]};
  const float* cw[2]     = {(const float*)d_in[22], (const float*)d_in[31]};
  const float* cb[2]     = {(const float*)d_in[23], (const float*)d_in[32]};
  const float* xp_w[2]   = {(const float*)d_in[24], (const float*)d_in[33]};
  const float* dt_w[2]   = {(const float*)d_in[25], (const float*)d_in[34]};
  const float* dt_b[2]   = {(const float*)d_in[26], (const float*)d_in[35]};
  const float* A_log[2]  = {(const float*)d_in[27], (const float*)d_in[36]};
  const float* Dp[2]     = {(const float*)d_in[28], (const float*)d_in[37]};
  const float* out_w[2]  = {(const float*)d_in[29], (const float*)d_in[38]};
  const float* ffn_g     = (const float*)d_in[39];
  const float* ffn_bb    = (const float*)d_in[40];
  const float* gate_w    = (const float*)d_in[41];
  const float* up_w      = (const float*)d_in[42];
  const float* down_w    = (const float*)d_in[43];

  float* ws = (float*)d_ws;
  size_t off = 0;
  const size_t M = 2048;
  auto take = [&](size_t n) { float* p = ws + off; off += n; return p; };
  float* QKV   = take(M * 2304);
  float* AO    = take(M * 768);
  float* AO2   = take(M * 768);
  float* GL    = take(M * 768);
  float* LOC   = take(M * 768);
  float* T1    = take(M * 768);
  float* X1    = take(M * 768);
  float* XN    = take(M * 768);
  float* XIZ   = take(M * 3072);
  float* XC    = take(M * 1536);
  float* DBC   = take(M * 80);
  float* DELTA = take(M * 1536);
  float* YG    = take(M * 1536);
  float* YF    = take(M * 768);
  float* YB    = take(M * 768);
  float* X2    = take(M * 768);
  float* SS    = take(2 * 1536 * 16 * 16);
  float* PP    = take(2 * 1536 * 16 * 16);
  float* HI    = take(2 * 1536 * 16 * 16);
  float* PART  = take((size_t)XP_KSPLIT * M * 80);
  float* GU    = XIZ;  // reuse (mamba finished before FFN)
  float* YFB[2] = {YF, YB};

  dim3 blk(256);

  // --- GLCE branch ---
  gemm_bf16_big<128><<<dim3(16 * 18), blk, 0, stream>>>(x, 768, 0, qkv_w, qkv_b, nullptr,
                                                        QKV, 2304, 0, 0, 2304, 768, 0, 0);
  attn_mfma<<<dim3(16, 16), blk, 0, stream>>>(QKV, AO);
  gemm_bf16_big<64><<<dim3(16 * 12), blk, 0, stream>>>(AO, 768, 0, att_out_w, att_out_b, nullptr,
                                                       AO2, 768, 0, 0, 768, 768, 0, 0);
  gemm_bf16_big<64><<<dim3(16 * 6), blk, 0, stream>>>(AO2, 768, 0, gproj_w, gproj_b, nullptr,
                                                      GL, 768, 0, 0, 384, 768, 0, 0);
  glce_conv<<<dim3(M * 768 / 256), blk, 0, stream>>>(x, conv3_w, conv3_b, conv5_w,
                                                     conv5_b, conv7_w, conv7_b, LOC);
  gemm_bf16_big<64><<<dim3(16 * 6), blk, 0, stream>>>(LOC, 768, 0, lproj_w, lproj_b, nullptr,
                                                      GL, 768, 384, 0, 384, 768, 0, 0);
  gemm_bf16_big<64><<<dim3(16 * 12), blk, 0, stream>>>(GL, 768, 0, fus_w, fus_b, x,
                                                       T1, 768, 0, 0, 768, 768, 0, 0);
  ln_f32<<<dim3(512), blk, 0, stream>>>(T1, glce_g, glce_bb, X1);

  // --- bidirectional mamba ---
  ln_f32<<<dim3(512), blk, 0, stream>>>(X1, ssm_g, ssm_bb, XN);
  for (int dir = 0; dir < 2; ++dir) {
    int flip = dir;
    gemm_bf16_big<128><<<dim3(16 * 24), blk, 0, stream>>>(XN, 768, flip, in_w[dir], nullptr, nullptr,
                                                          XIZ, 3072, 0, 0, 3072, 768, 0, 0);
    mamba_conv_f32<<<dim3(M * 1536 / 256), blk, 0, stream>>>(XIZ, cw[dir], cb[dir], XC);
    xp_part<<<dim3(32, XP_KSPLIT), blk, 0, stream>>>(XC, xp_w[dir], PART);
    xp_reduce<<<dim3(M * 80 / 256), blk, 0, stream>>>(PART, DBC);
    gemm_f32<<<dim3(24, 32), blk, 0, stream>>>(DBC, 80, 0, dt_w[dir], dt_b[dir], nullptr,
                                               DELTA, 1536, 0, 0, 1536, 48, 1, 0);
    mamba_scan_part<<<dim3(3072), blk, 0, stream>>>(DBC, DELTA, XC, A_log[dir], SS, PP);
    mamba_scan_comb<<<dim3(192), blk, 0, stream>>>(SS, PP, HI);
    mamba_scan_fin<<<dim3(3072), blk, 0, stream>>>(DBC, DELTA, XC, XIZ, A_log[dir],
                                                   Dp[dir], HI, YG);
    gemm_bf16_big<64><<<dim3(16 * 12), blk, 0, stream>>>(YG, 1536, 0, out_w[dir], nullptr, nullptr,
                                                         YFB[dir], 768, 0, flip, 768, 1536, 0, 0);
  }
  add3_f32<<<dim3(M * 768 / 256), blk, 0, stream>>>(X1, YF, YB, X2);

  // --- FFN ---
  ln_f32<<<dim3(512), blk, 0, stream>>>(X2, ffn_g, ffn_bb, XN);
  gemm_bf16_big<128><<<dim3(16 * 24), blk, 0, stream>>>(XN, 768, 0, gate_w, nullptr, nullptr,
                                                        GU, 3072, 0, 0, 3072, 768, 2, 0);
  gemm_bf16_big<128><<<dim3(16 * 24), blk, 0, stream>>>(XN, 768, 0, up_w, nullptr, nullptr,
                                                        GU, 3072, 0, 0, 3072, 768, 0, 1);
  gemm_bf16_big<64><<<dim3(16 * 12), blk, 0, stream>>>(GU, 3072, 0, down_w, nullptr, X2,
                                                       (float*)d_out, 768, 0, 0, 768, 3072, 0, 0);
}

// Round 7
// 798.129 us; speedup vs baseline: 1.6644x; 1.6644x over previous
//
#include <hip/hip_runtime.h>
#include <math.h>

#define LSEQ 1024
#define DMODEL 768
#define NHEAD 8
#define HDIM 96
#define DI_ 1536
#define NST 16
#define DTR_ 48
#define FF_ 3072

typedef unsigned short u16;
typedef __attribute__((ext_vector_type(8))) short short8;
typedef __attribute__((ext_vector_type(4))) short short4_t;
typedef __attribute__((ext_vector_type(4))) float f32x4;

__device__ inline short f2bf(float f) {
  unsigned u = __builtin_bit_cast(unsigned, f);
  unsigned r = u + 0x7FFFu + ((u >> 16) & 1u);   // round-to-nearest-even
  return (short)(r >> 16);
}
__device__ inline float bf2f(u16 b) {
  return __builtin_bit_cast(float, (unsigned)b << 16);
}

// ---------------------------------------------------------------------------
// fp32 -> bf16 conversion (weights / x), 4 elems per thread
// ---------------------------------------------------------------------------
__global__ __launch_bounds__(256) void cvt_bf16(const float* __restrict__ s,
                                                u16* __restrict__ d, int n)
{
  int i = (blockIdx.x * 256 + threadIdx.x) * 4;
  if (i >= n) return;
  float4 v = *(const float4*)(s + i);
  *(short4_t*)(d + i) = short4_t{f2bf(v.x), f2bf(v.y), f2bf(v.z), f2bf(v.w)};
}

// ---------------------------------------------------------------------------
// bf16 MFMA GEMM, tile 128x128, BK=64, 4 waves (64x64 quadrant each).
// A (2048 x lda) bf16, W (Ncols x Kd) bf16 row-major. Requires Ncols%128==0,
// Kd%64==0. Register-prefetch pipelined; XOR-swizzled LDS (T2); grouped
// block order for L2 (GROUP_M=4).
// OUTMODE: 0 = f32 store (+optional residual), 1 = bf16 store, 2 = bf16 *=
// act: 0 none, 1 softplus, 2 silu
// ---------------------------------------------------------------------------
template<int OUTMODE>
__global__ __launch_bounds__(256) void gemm_mx(
    const u16* __restrict__ A, int lda, int flipA,
    const u16* __restrict__ W,
    const float* __restrict__ bias,
    const float* __restrict__ residual,
    void* __restrict__ Cv, int ldc, int colOff, int flipC,
    int Ncols, int Kd, int act)
{
  __shared__ u16 As[128 * 64];
  __shared__ u16 Bs[128 * 64];

  const int ncl = Ncols >> 7;
  const int ppg = 4 * ncl;
  const int rm = (blockIdx.x / ppg) * 4 + (blockIdx.x % ppg) % 4;
  const int cn = (blockIdx.x % ppg) / 4;
  const int row0 = rm << 7, col0 = cn << 7;

  const int tid = threadIdx.x;
  const int w = tid >> 6, lane = tid & 63;
  const int m16 = lane & 15, kg = lane >> 4;
  const int wr = w >> 1, wc = w & 1;

  // staging: thread covers rows {u*32 + tid>>3}, col-group tid&7 (8 bf16=16B)
  const int sr = tid >> 3;
  const int scg = tid & 7;
  const u16* aptr[4];
  const u16* wptr[4];
  int wof[4];
  #pragma unroll
  for (int u = 0; u < 4; ++u) {
    int gm = row0 + u * 32 + sr;
    int bb = gm >> 10, ll = gm & 1023;
    if (flipA) ll = 1023 - ll;
    aptr[u] = A + (size_t)(bb * 1024 + ll) * lda + scg * 8;
    wptr[u] = W + (size_t)(col0 + u * 32 + sr) * Kd + scg * 8;
    int r = u * 32 + sr;
    wof[u] = r * 64 + ((scg ^ (r & 7)) << 3);    // XOR-swizzled write offset
  }

  f32x4 acc[4][4] = {};

  short8 ra[4], rw[4];
  #pragma unroll
  for (int u = 0; u < 4; ++u) {
    ra[u] = *(const short8*)(aptr[u]);
    rw[u] = *(const short8*)(wptr[u]);
  }

  const int nK = Kd >> 6;
  for (int kt = 0; kt < nK; ++kt) {
    __syncthreads();                      // prior iter's LDS reads done
    #pragma unroll
    for (int u = 0; u < 4; ++u) {
      *(short8*)&As[wof[u]] = ra[u];
      *(short8*)&Bs[wof[u]] = rw[u];
    }
    __syncthreads();
    if (kt + 1 < nK) {                    // prefetch next K-tile into regs
      int ko = (kt + 1) << 6;
      #pragma unroll
      for (int u = 0; u < 4; ++u) {
        ra[u] = *(const short8*)(aptr[u] + ko);
        rw[u] = *(const short8*)(wptr[u] + ko);
      }
    }
    #pragma unroll
    for (int ks = 0; ks < 2; ++ks) {
      short8 af[4], bf[4];
      #pragma unroll
      for (int mi = 0; mi < 4; ++mi) {
        int r = wr * 64 + mi * 16 + m16;
        int cg = (ks * 4 + kg) ^ (r & 7);
        af[mi] = *(const short8*)&As[r * 64 + cg * 8];
      }
      #pragma unroll
      for (int ni = 0; ni < 4; ++ni) {
        int r = wc * 64 + ni * 16 + m16;
        int cg = (ks * 4 + kg) ^ (r & 7);
        bf[ni] = *(const short8*)&Bs[r * 64 + cg * 8];
      }
      #pragma unroll
      for (int mi = 0; mi < 4; ++mi)
        #pragma unroll
        for (int ni = 0; ni < 4; ++ni)
          acc[mi][ni] = __builtin_amdgcn_mfma_f32_16x16x32_bf16(af[mi], bf[ni],
                                                                acc[mi][ni], 0, 0, 0);
    }
  }

  #pragma unroll
  for (int ni = 0; ni < 4; ++ni) {
    int gn = col0 + wc * 64 + ni * 16 + m16;
    float bv = bias ? bias[gn] : 0.f;
    #pragma unroll
    for (int mi = 0; mi < 4; ++mi) {
      #pragma unroll
      for (int r = 0; r < 4; ++r) {
        int gm = row0 + wr * 64 + mi * 16 + (kg << 2) + r;
        int bb = gm >> 10, ll = gm & 1023;
        if (flipC) ll = 1023 - ll;
        float v = acc[mi][ni][r] + bv;
        if (act == 1) v = fmaxf(v, 0.f) + log1pf(__expf(-fabsf(v)));   // softplus
        else if (act == 2) v = v / (1.f + __expf(-v));                 // silu
        size_t idx = (size_t)(bb * 1024 + ll) * ldc + colOff + gn;
        if (OUTMODE == 0) {
          float* C = (float*)Cv;
          C[idx] = residual ? residual[idx] + v : v;
        } else if (OUTMODE == 1) {
          ((u16*)Cv)[idx] = (u16)f2bf(v);
        } else {
          u16* C = (u16*)Cv;
          C[idx] = (u16)f2bf(bf2f(C[idx]) * v);
        }
      }
    }
  }
}

// ---------------------------------------------------------------------------
// fp32 GEMM (kept for the dt projection: K=48)
// ---------------------------------------------------------------------------
__global__ __launch_bounds__(256) void gemm_f32(
    const float* __restrict__ A, int lda, int flipA,
    const float* __restrict__ W,
    const float* __restrict__ bias,
    const float* __restrict__ residual,
    float* __restrict__ C, int ldc, int colOff, int flipC,
    int Ncols, int Kd, int act, int mulC)
{
  __shared__ float As[16][65];
  __shared__ float Bs[16][65];
  const int row0 = blockIdx.y * 64, col0 = blockIdx.x * 64;
  const int tid = threadIdx.x;
  const int tx = tid & 15, ty = tid >> 4;
  float acc[4][4] = {};
  const int lm = tid >> 2;
  const int lk = (tid & 3) << 2;
  int gmL = row0 + lm;
  int bbL = gmL >> 10, llL = gmL & 1023;
  if (flipA) llL = LSEQ - 1 - llL;
  const float* arow = A + (size_t)(bbL * LSEQ + llL) * lda;
  int gnL = col0 + lm;
  const bool wvalid = (gnL < Ncols);
  const float* wrow = W + (size_t)(wvalid ? gnL : 0) * Kd;

  for (int k0 = 0; k0 < Kd; k0 += 16) {
    #pragma unroll
    for (int u = 0; u < 4; ++u) {
      int kkk = k0 + lk + u;
      bool kin = (kkk < Kd);
      As[lk + u][lm] = kin ? arow[kkk] : 0.f;
      Bs[lk + u][lm] = (kin && wvalid) ? wrow[kkk] : 0.f;
    }
    __syncthreads();
    #pragma unroll
    for (int kkk = 0; kkk < 16; ++kkk) {
      float a[4], bv[4];
      #pragma unroll
      for (int i = 0; i < 4; ++i) a[i] = As[kkk][(ty << 2) + i];
      #pragma unroll
      for (int j = 0; j < 4; ++j) bv[j] = Bs[kkk][(tx << 2) + j];
      #pragma unroll
      for (int i = 0; i < 4; ++i)
        #pragma unroll
        for (int j = 0; j < 4; ++j)
          acc[i][j] = fmaf(a[i], bv[j], acc[i][j]);
    }
    __syncthreads();
  }

  #pragma unroll
  for (int i = 0; i < 4; ++i) {
    int gm = row0 + (ty << 2) + i;
    int bb = gm >> 10, ll = gm & 1023;
    if (flipC) ll = LSEQ - 1 - ll;
    size_t base = (size_t)(bb * LSEQ + ll) * ldc + colOff;
    #pragma unroll
    for (int j = 0; j < 4; ++j) {
      int gn = col0 + (tx << 2) + j;
      if (gn >= Ncols) continue;
      float v = acc[i][j];
      if (bias) v += bias[gn];
      if (act == 1) v = fmaxf(v, 0.f) + log1pf(__expf(-fabsf(v)));
      else if (act == 2) v = v / (1.f + __expf(-v));
      size_t idx = base + gn;
      if (mulC) C[idx] *= v;
      else if (residual) C[idx] = residual[idx] + v;
      else C[idx] = v;
    }
  }
}

// ---------------------------------------------------------------------------
// Split-K fp32 GEMM for the skinny xp projection (M=2048, N=80, K=1536).
// ---------------------------------------------------------------------------
#define XP_KSPLIT 8
#define XP_KCH 192
__global__ __launch_bounds__(256) void xp_part(
    const float* __restrict__ A, const float* __restrict__ W,
    float* __restrict__ PART)
{
  __shared__ float As[64][34];
  __shared__ float Ws[80][34];
  const int tid = threadIdx.x;
  const int row0 = blockIdx.x * 64;
  const int kbase = blockIdx.y * XP_KCH;
  const int ty = tid >> 4, tx = tid & 15;

  float acc[4][5] = {};

  for (int ch = 0; ch < XP_KCH; ch += 32) {
    const int gk = kbase + ch;
    __syncthreads();
    #pragma unroll
    for (int u = 0; u < 2; ++u) {
      int i = tid + u * 256;
      int r = i >> 3, k4 = (i & 7) << 2;
      *(float4*)&As[r][k4] = *(const float4*)&A[(size_t)(row0 + r) * 1536 + gk + k4];
    }
    #pragma unroll
    for (int u = 0; u < 3; ++u) {
      int j = tid + u * 256;
      if (j < 640) {
        int c = j >> 3, k4 = (j & 7) << 2;
        *(float4*)&Ws[c][k4] = *(const float4*)&W[(size_t)c * 1536 + gk + k4];
      }
    }
    __syncthreads();
    #pragma unroll
    for (int k = 0; k < 32; k += 2) {
      float2 a2[4], w2[5];
      #pragma unroll
      for (int i = 0; i < 4; ++i) a2[i] = *(const float2*)&As[ty + 16 * i][k];
      #pragma unroll
      for (int j = 0; j < 5; ++j) w2[j] = *(const float2*)&Ws[tx + 16 * j][k];
      #pragma unroll
      for (int i = 0; i < 4; ++i)
        #pragma unroll
        for (int j = 0; j < 5; ++j) {
          acc[i][j] = fmaf(a2[i].x, w2[j].x, acc[i][j]);
          acc[i][j] = fmaf(a2[i].y, w2[j].y, acc[i][j]);
        }
    }
  }

  float* pbase = PART + (size_t)blockIdx.y * 2048 * 80;
  #pragma unroll
  for (int i = 0; i < 4; ++i) {
    int gr = row0 + ty + 16 * i;
    #pragma unroll
    for (int j = 0; j < 5; ++j)
      pbase[(size_t)gr * 80 + tx + 16 * j] = acc[i][j];
  }
}

__global__ __launch_bounds__(256) void xp_reduce(
    const float* __restrict__ PART, float* __restrict__ DBC)
{
  int t = blockIdx.x * 256 + threadIdx.x;
  float s = 0.f;
  #pragma unroll
  for (int ks = 0; ks < XP_KSPLIT; ++ks)
    s += PART[(size_t)ks * 2048 * 80 + t];
  DBC[t] = s;
}

// ---------------------------------------------------------------------------
// MFMA flash attention. One block = one (b,h) x 64 q rows; 4 waves x 16 rows.
// Output written as bf16 (feeds attn_out GEMM only).
// ---------------------------------------------------------------------------
__global__ __launch_bounds__(256) void attn_mfma(const float* __restrict__ qkv,
                                                 u16* __restrict__ o)
{
  __shared__ short Ks[64][104];
  __shared__ short Vt[96][72];
  __shared__ short Ps[4][16][72];

  const int bh = blockIdx.y;
  const int b_ = bh >> 3, h = bh & 7;
  const int q0 = blockIdx.x * 64;
  const int tid = threadIdx.x;
  const int w = tid >> 6, lane = tid & 63;
  const int m16 = lane & 15, g4 = lane >> 4;

  const float sc2 = 0.10206207261596577f * 1.4426950408889634f;

  short8 qf[3];
  {
    const float* qrow = qkv + ((size_t)(b_ * LSEQ) + q0 + w * 16 + m16) * 2304 + h * HDIM;
    #pragma unroll
    for (int c = 0; c < 3; ++c) {
      float4 v0 = *(const float4*)(qrow + c * 32 + g4 * 8);
      float4 v1 = *(const float4*)(qrow + c * 32 + g4 * 8 + 4);
      qf[c] = short8{f2bf(v0.x), f2bf(v0.y), f2bf(v0.z), f2bf(v0.w),
                     f2bf(v1.x), f2bf(v1.y), f2bf(v1.z), f2bf(v1.w)};
    }
  }

  float m_run[4], l_run[4];
  #pragma unroll
  for (int r = 0; r < 4; ++r) { m_run[r] = -INFINITY; l_run[r] = 0.f; }
  f32x4 oacc[6];
  #pragma unroll
  for (int ct = 0; ct < 6; ++ct) oacc[ct] = (f32x4)(0.f);

  const int kr = tid >> 2;
  const int cc = (tid & 3) * 24;

  for (int t = 0; t < LSEQ / 64; ++t) {
    const int k0 = t * 64;
    __syncthreads();
    {
      const float* kp = qkv + ((size_t)(b_ * LSEQ) + k0 + kr) * 2304 + DMODEL + h * HDIM + cc;
      const float* vp = kp + DMODEL;
      #pragma unroll
      for (int u = 0; u < 6; ++u) {
        float4 kv = *(const float4*)(kp + u * 4);
        *(short4_t*)&Ks[kr][cc + u * 4] =
            short4_t{f2bf(kv.x), f2bf(kv.y), f2bf(kv.z), f2bf(kv.w)};
        float4 vv = *(const float4*)(vp + u * 4);
        Vt[cc + u * 4 + 0][kr] = f2bf(vv.x);
        Vt[cc + u * 4 + 1][kr] = f2bf(vv.y);
        Vt[cc + u * 4 + 2][kr] = f2bf(vv.z);
        Vt[cc + u * 4 + 3][kr] = f2bf(vv.w);
      }
    }
    __syncthreads();

    f32x4 sacc[4];
    #pragma unroll
    for (int kt = 0; kt < 4; ++kt) sacc[kt] = (f32x4)(0.f);
    #pragma unroll
    for (int c = 0; c < 3; ++c) {
      #pragma unroll
      for (int kt = 0; kt < 4; ++kt) {
        short8 bfrag = *(const short8*)&Ks[kt * 16 + m16][c * 32 + g4 * 8];
        sacc[kt] = __builtin_amdgcn_mfma_f32_16x16x32_bf16(qf[c], bfrag, sacc[kt], 0, 0, 0);
      }
    }

    #pragma unroll
    for (int r = 0; r < 4; ++r) {
      float s0 = sacc[0][r] * sc2, s1 = sacc[1][r] * sc2;
      float s2v = sacc[2][r] * sc2, s3 = sacc[3][r] * sc2;
      float mv = fmaxf(fmaxf(s0, s1), fmaxf(s2v, s3));
      mv = fmaxf(mv, __shfl_xor(mv, 1));
      mv = fmaxf(mv, __shfl_xor(mv, 2));
      mv = fmaxf(mv, __shfl_xor(mv, 4));
      mv = fmaxf(mv, __shfl_xor(mv, 8));
      float mnew = fmaxf(m_run[r], mv);
      float scale = exp2f(m_run[r] - mnew);
      float p0 = exp2f(s0 - mnew), p1 = exp2f(s1 - mnew);
      float p2 = exp2f(s2v - mnew), p3 = exp2f(s3 - mnew);
      short* pr = &Ps[w][g4 * 4 + r][m16];
      pr[0]  = f2bf(p0);
      pr[16] = f2bf(p1);
      pr[32] = f2bf(p2);
      pr[48] = f2bf(p3);
      float ps = p0 + p1 + p2 + p3;
      ps += __shfl_xor(ps, 1);
      ps += __shfl_xor(ps, 2);
      ps += __shfl_xor(ps, 4);
      ps += __shfl_xor(ps, 8);
      l_run[r] = l_run[r] * scale + ps;
      m_run[r] = mnew;
      #pragma unroll
      for (int ct = 0; ct < 6; ++ct) oacc[ct][r] *= scale;
    }

    #pragma unroll
    for (int kc = 0; kc < 2; ++kc) {
      short8 pa = *(const short8*)&Ps[w][m16][kc * 32 + g4 * 8];
      #pragma unroll
      for (int ct = 0; ct < 6; ++ct) {
        short8 vb = *(const short8*)&Vt[ct * 16 + m16][kc * 32 + g4 * 8];
        oacc[ct] = __builtin_amdgcn_mfma_f32_16x16x32_bf16(pa, vb, oacc[ct], 0, 0, 0);
      }
    }
  }

  #pragma unroll
  for (int r = 0; r < 4; ++r) {
    float inv = 1.f / l_run[r];
    u16* orow = o + ((size_t)(b_ * LSEQ) + q0 + w * 16 + g4 * 4 + r) * DMODEL + h * HDIM;
    #pragma unroll
    for (int ct = 0; ct < 6; ++ct)
      orow[ct * 16 + m16] = (u16)f2bf(oacc[ct][r] * inv);
  }
}

// ---------------------------------------------------------------------------
// GLCE convs (kernels 3/5/7, 3 in-ch per out-ch, exact gelu) -> bf16
// ---------------------------------------------------------------------------
__global__ __launch_bounds__(256) void glce_conv(
    const float* __restrict__ x,
    const float* __restrict__ w3, const float* __restrict__ b3,
    const float* __restrict__ w5, const float* __restrict__ b5,
    const float* __restrict__ w7, const float* __restrict__ b7,
    u16* __restrict__ loc)
{
  int idx = blockIdx.x * 256 + threadIdx.x;
  int c = idx % DMODEL;
  int bl = idx / DMODEL;
  int l = bl & 1023, b_ = bl >> 10;
  int cs = c >> 8, ch = c & 255;
  const float* wp; float bias; int kt, pad;
  if (cs == 0)      { wp = w3 + ch * 9;  bias = b3[ch]; kt = 3; pad = 1; }
  else if (cs == 1) { wp = w5 + ch * 15; bias = b5[ch]; kt = 5; pad = 2; }
  else              { wp = w7 + ch * 21; bias = b7[ch]; kt = 7; pad = 3; }
  float acc = bias;
  const float* xb = x + (size_t)(b_ * LSEQ) * DMODEL;
  for (int i = 0; i < 3; ++i) {
    int d = 3 * ch + i;
    for (int t = 0; t < kt; ++t) {
      int ls = l - pad + t;
      if (ls >= 0 && ls < LSEQ)
        acc = fmaf(xb[(size_t)ls * DMODEL + d], wp[i * kt + t], acc);
    }
  }
  loc[idx] = (u16)f2bf(0.5f * acc * (1.f + erff(acc * 0.7071067811865475f)));
}

// ---------------------------------------------------------------------------
// Mamba depthwise causal conv (K=4) + silu
// ---------------------------------------------------------------------------
__global__ __launch_bounds__(256) void mamba_conv_f32(
    const float* __restrict__ xiz, const float* __restrict__ cw,
    const float* __restrict__ cb, float* __restrict__ xc)
{
  int idx = blockIdx.x * 256 + threadIdx.x;
  int d = idx % DI_;
  int bl = idx / DI_;
  int l = bl & 1023, b_ = bl >> 10;
  const float* w = cw + d * 4;
  float acc = cb[d];
  #pragma unroll
  for (int t = 0; t < 4; ++t) {
    int ls = l - 3 + t;
    if (ls >= 0)
      acc = fmaf(xiz[((size_t)(b_ * LSEQ + ls)) * 3072 + d], w[t], acc);
  }
  xc[idx] = acc / (1.f + __expf(-acc));
}

// ---------------------------------------------------------------------------
// Chunked selective scan. CHUNK=64, NCHUNK=16.
// ---------------------------------------------------------------------------
__global__ __launch_bounds__(256) void mamba_scan_part(
    const float* __restrict__ dbc, const float* __restrict__ delta,
    const float* __restrict__ xc, const float* __restrict__ A_log,
    float* __restrict__ SS, float* __restrict__ PP)
{
  const int bc = blockIdx.x;
  const int b_ = bc / (96 * 16);
  const int rem = bc % (96 * 16);
  const int d0 = (rem >> 4) << 4;
  const int ck = rem & 15;
  const int tid = threadIdx.x;
  const int dl = tid >> 4, n = tid & 15;
  const int d = d0 + dl;
  const float a2 = -__expf(A_log[d * 16 + n]) * 1.4426950408889634f;

  __shared__ float sdel[64][16];
  __shared__ float sxc[64][16];
  __shared__ float sB[64][16];
  const size_t rowb = (size_t)b_ * LSEQ + ck * 64;

  #pragma unroll
  for (int k = 0; k < 4; ++k) {
    int i = tid + k * 256;
    int lc = i >> 4, c = i & 15;
    size_t row = rowb + lc;
    sdel[lc][c] = delta[row * 1536 + d0 + c];
    sxc[lc][c]  = xc[row * 1536 + d0 + c];
    sB[lc][c]   = dbc[row * 80 + 48 + c];
  }
  __syncthreads();

  float h = 0.f, sumd = 0.f;
  for (int lc = 0; lc < 64; ++lc) {
    float dlv = sdel[lc][dl];
    float xv  = sxc[lc][dl];
    float dA = exp2f(dlv * a2);
    h = fmaf(dA, h, dlv * xv * sB[lc][n]);
    sumd += dlv;
  }
  size_t idx = (((size_t)b_ * 1536 + d) * 16 + ck) * 16 + n;
  SS[idx] = h;
  PP[idx] = exp2f(a2 * sumd);
}

__global__ __launch_bounds__(256) void mamba_scan_comb(
    const float* __restrict__ SS, const float* __restrict__ PP,
    float* __restrict__ HI)
{
  int t = blockIdx.x * 256 + threadIdx.x;
  size_t base = (size_t)(t >> 4) * 256 + (t & 15);
  float run = 0.f;
  #pragma unroll
  for (int c = 0; c < 16; ++c) {
    size_t idx = base + c * 16;
    HI[idx] = run;
    run = fmaf(PP[idx], run, SS[idx]);
  }
}

__global__ __launch_bounds__(256) void mamba_scan_fin(
    const float* __restrict__ dbc, const float* __restrict__ delta,
    const float* __restrict__ xc, const float* __restrict__ xiz,
    const float* __restrict__ A_log, const float* __restrict__ Dp,
    const float* __restrict__ HI, u16* __restrict__ yg)
{
  const int bc = blockIdx.x;
  const int b_ = bc / (96 * 16);
  const int rem = bc % (96 * 16);
  const int d0 = (rem >> 4) << 4;
  const int ck = rem & 15;
  const int tid = threadIdx.x;
  const int dl = tid >> 4, n = tid & 15;
  const int d = d0 + dl;
  const float a2 = -__expf(A_log[d * 16 + n]) * 1.4426950408889634f;
  const float dv = Dp[d];

  __shared__ float sdel[64][16];
  __shared__ float sxc[64][16];
  __shared__ float sz[64][16];
  __shared__ float sB[64][16];
  __shared__ float sC[64][16];
  __shared__ float sy[64][16];
  const size_t rowb = (size_t)b_ * LSEQ + ck * 64;

  #pragma unroll
  for (int k = 0; k < 4; ++k) {
    int i = tid + k * 256;
    int lc = i >> 4, c = i & 15;
    size_t row = rowb + lc;
    sdel[lc][c] = delta[row * 1536 + d0 + c];
    sxc[lc][c]  = xc[row * 1536 + d0 + c];
    sz[lc][c]   = xiz[row * 3072 + 1536 + d0 + c];
    sB[lc][c]   = dbc[row * 80 + 48 + c];
    sC[lc][c]   = dbc[row * 80 + 64 + c];
  }
  __syncthreads();

  float h = HI[(((size_t)b_ * 1536 + d) * 16 + ck) * 16 + n];
  for (int lc = 0; lc < 64; ++lc) {
    float dlv = sdel[lc][dl];
    float xv  = sxc[lc][dl];
    float dA = exp2f(dlv * a2);
    h = fmaf(dA, h, dlv * xv * sB[lc][n]);
    float p = h * sC[lc][n];
    p += __shfl_xor(p, 1);
    p += __shfl_xor(p, 2);
    p += __shfl_xor(p, 4);
    p += __shfl_xor(p, 8);
    if (n == 0) {
      float zv = sz[lc][dl];
      float y = p + xv * dv;
      sy[lc][dl] = y * (zv / (1.f + __expf(-zv)));
    }
  }
  __syncthreads();
  #pragma unroll
  for (int k = 0; k < 4; ++k) {
    int i = tid + k * 256;
    int lc = i >> 4, c = i & 15;
    yg[(rowb + lc) * 1536 + d0 + c] = (u16)f2bf(sy[lc][c]);
  }
}

// ---------------------------------------------------------------------------
// LayerNorm over last dim (768): fp32-out and bf16-out variants
// ---------------------------------------------------------------------------
__global__ __launch_bounds__(256) void ln_f32(
    const float* __restrict__ in, const float* __restrict__ g,
    const float* __restrict__ b, float* __restrict__ out)
{
  int row = blockIdx.x * 4 + (threadIdx.x >> 6);
  int lane = threadIdx.x & 63;
  const float* xr = in + (size_t)row * DMODEL;
  float v[12];
  float s = 0.f, s2 = 0.f;
  #pragma unroll
  for (int i = 0; i < 12; ++i) {
    float t = xr[i * 64 + lane];
    v[i] = t; s += t; s2 = fmaf(t, t, s2);
  }
  #pragma unroll
  for (int off = 1; off < 64; off <<= 1) {
    s += __shfl_xor(s, off);
    s2 += __shfl_xor(s2, off);
  }
  float mean = s * (1.f / 768.f);
  float var = s2 * (1.f / 768.f) - mean * mean;
  float inv = rsqrtf(var + 1e-5f);
  float* orow = out + (size_t)row * DMODEL;
  #pragma unroll
  for (int i = 0; i < 12; ++i) {
    int c = i * 64 + lane;
    orow[c] = (v[i] - mean) * inv * g[c] + b[c];
  }
}

__global__ __launch_bounds__(256) void ln_bf16(
    const float* __restrict__ in, const float* __restrict__ g,
    const float* __restrict__ b, u16* __restrict__ out)
{
  int row = blockIdx.x * 4 + (threadIdx.x >> 6);
  int lane = threadIdx.x & 63;
  const float* xr = in + (size_t)row * DMODEL;
  float v[12];
  float s = 0.f, s2 = 0.f;
  #pragma unroll
  for (int i = 0; i < 12; ++i) {
    float t = xr[i * 64 + lane];
    v[i] = t; s += t; s2 = fmaf(t, t, s2);
  }
  #pragma unroll
  for (int off = 1; off < 64; off <<= 1) {
    s += __shfl_xor(s, off);
    s2 += __shfl_xor(s2, off);
  }
  float mean = s * (1.f / 768.f);
  float var = s2 * (1.f / 768.f) - mean * mean;
  float inv = rsqrtf(var + 1e-5f);
  u16* orow = out + (size_t)row * DMODEL;
  #pragma unroll
  for (int i = 0; i < 12; ++i) {
    int c = i * 64 + lane;
    orow[c] = (u16)f2bf((v[i] - mean) * inv * g[c] + b[c]);
  }
}

__global__ __launch_bounds__(256) void add3_f32(
    const float* __restrict__ a, const float* __restrict__ b,
    const float* __restrict__ c, float* __restrict__ o)
{
  int i = blockIdx.x * 256 + threadIdx.x;
  o[i] = a[i] + b[i] + c[i];
}

// ---------------------------------------------------------------------------
extern "C" void kernel_launch(void* const* d_in, const int* in_sizes, int n_in,
                              void* d_out, int out_size, void* d_ws, size_t ws_size,
                              hipStream_t stream)
{
  (void)in_sizes; (void)n_in; (void)out_size; (void)ws_size;
  const float* x         = (const float*)d_in[0];
  const float* qkv_w     = (const float*)d_in[1];
  const float* qkv_b     = (const float*)d_in[2];
  const float* att_out_w = (const float*)d_in[3];
  const float* att_out_b = (const float*)d_in[4];
  const float* conv3_w   = (const float*)d_in[5];
  const float* conv3_b   = (const float*)d_in[6];
  const float* conv5_w   = (const float*)d_in[7];
  const float* conv5_b   = (const float*)d_in[8];
  const float* conv7_w   = (const float*)d_in[9];
  const float* conv7_b   = (const float*)d_in[10];
  const float* gproj_w   = (const float*)d_in[11];
  const float* gproj_b   = (const float*)d_in[12];
  const float* lproj_w   = (const float*)d_in[13];
  const float* lproj_b   = (const float*)d_in[14];
  const float* fus_w     = (const float*)d_in[15];
  const float* fus_b     = (const float*)d_in[16];
  const float* glce_g    = (const float*)d_in[17];
  const float* glce_bb   = (const float*)d_in[18];
  const float* ssm_g     = (const float*)d_in[19];
  const float* ssm_bb    = (const float*)d_in[20];
  const float* in_w[2]   = {(const float*)d_in[21], (const float*)d_in[30]};
  const float* cw[2]     = {(const float*)d_in[22], (const float*)d_in[31]};
  const float* cb[2]     = {(const float*)d_in[23], (const float*)d_in[32]};
  const float* xp_w[2]   = {(const float*)d_in[24], (const float*)d_in[33]};
  const float* dt_w[2]   = {(const float*)d_in[25], (const float*)d_in[34]};
  const float* dt_b[2]   = {(const float*)d_in[26], (const float*)d_in[35]};
  const float* A_log[2]  = {(const float*)d_in[27], (const float*)d_in[36]};
  const float* Dp[2]     = {(const float*)d_in[28], (const float*)d_in[37]};
  const float* out_w[2]  = {(const float*)d_in[29], (const float*)d_in[38]};
  const float* ffn_g     = (const float*)d_in[39];
  const float* ffn_bb    = (const float*)d_in[40];
  const float* gate_w    = (const float*)d_in[41];
  const float* up_w      = (const float*)d_in[42];
  const float* down_w    = (const float*)d_in[43];

  float* ws = (float*)d_ws;
  size_t off = 0;
  const size_t M = 2048;
  auto take = [&](size_t n) { float* p = ws + off; off += n; return p; };
  auto takeb = [&](size_t n) { u16* p = (u16*)(ws + off); off += (n + 1) / 2; return p; };

  float* QKV   = take(M * 2304);
  float* T1    = take(M * 768);
  float* X1    = take(M * 768);
  float* XIZ   = take(M * 3072);
  float* XC    = take(M * 1536);
  float* DBC   = take(M * 80);
  float* DELTA = take(M * 1536);
  float* YF    = take(M * 768);
  float* YB    = take(M * 768);
  float* X2    = take(M * 768);
  float* SS    = take(2 * 1536 * 16 * 16);
  float* PP    = take(2 * 1536 * 16 * 16);
  float* HI    = take(2 * 1536 * 16 * 16);
  float* PART  = take((size_t)XP_KSPLIT * M * 80);

  u16* Xbf   = takeb(M * 768);
  u16* AObf  = takeb(M * 768);
  u16* AO2bf = takeb(M * 768);
  u16* GLbf  = takeb(M * 768);
  u16* LOCbf = takeb(M * 768);
  u16* XNbf  = takeb(M * 768);
  u16* YGbf  = takeb(M * 1536);
  u16* GUbf  = (u16*)XIZ;            // alias: XIZ fully consumed before FFN

  // bf16 weights
  u16* wQKV  = takeb(2304 * 768);
  u16* wAT   = takeb(768 * 768);
  u16* wGP   = takeb(384 * 768);
  u16* wLP   = takeb(384 * 768);
  u16* wFU   = takeb(768 * 768);
  u16* wIN[2]  = {takeb(3072 * 768), takeb(3072 * 768)};
  u16* wOUT[2] = {takeb(768 * 1536), takeb(768 * 1536)};
  u16* wGA   = takeb(3072 * 768);
  u16* wUP   = takeb(3072 * 768);
  u16* wDN   = takeb(768 * 3072);

  float* YFB[2] = {YF, YB};
  dim3 blk(256);

  // --- weight + input conversions ---
  auto cvt = [&](const float* s, u16* d, int n) {
    cvt_bf16<<<dim3(n / 1024), blk, 0, stream>>>(s, d, n);
  };
  cvt(x, Xbf, M * 768);
  cvt(qkv_w, wQKV, 2304 * 768);
  cvt(att_out_w, wAT, 768 * 768);
  cvt(gproj_w, wGP, 384 * 768);
  cvt(lproj_w, wLP, 384 * 768);
  cvt(fus_w, wFU, 768 * 768);
  cvt(in_w[0], wIN[0], 3072 * 768);
  cvt(in_w[1], wIN[1], 3072 * 768);
  cvt(out_w[0], wOUT[0], 768 * 1536);
  cvt(out_w[1], wOUT[1], 768 * 1536);
  cvt(gate_w, wGA, 3072 * 768);
  cvt(up_w, wUP, 3072 * 768);
  cvt(down_w, wDN, 768 * 3072);

  // --- GLCE branch ---
  gemm_mx<0><<<dim3(16 * 18), blk, 0, stream>>>(Xbf, 768, 0, wQKV, qkv_b, nullptr,
                                                QKV, 2304, 0, 0, 2304, 768, 0);
  attn_mfma<<<dim3(16, 16), blk, 0, stream>>>(QKV, AObf);
  gemm_mx<1><<<dim3(16 * 6), blk, 0, stream>>>(AObf, 768, 0, wAT, att_out_b, nullptr,
                                               AO2bf, 768, 0, 0, 768, 768, 0);
  gemm_mx<1><<<dim3(16 * 3), blk, 0, stream>>>(AO2bf, 768, 0, wGP, gproj_b, nullptr,
                                               GLbf, 768, 0, 0, 384, 768, 0);
  glce_conv<<<dim3(M * 768 / 256), blk, 0, stream>>>(x, conv3_w, conv3_b, conv5_w,
                                                     conv5_b, conv7_w, conv7_b, LOCbf);
  gemm_mx<1><<<dim3(16 * 3), blk, 0, stream>>>(LOCbf, 768, 0, wLP, lproj_b, nullptr,
                                               GLbf, 768, 384, 0, 384, 768, 0);
  gemm_mx<0><<<dim3(16 * 6), blk, 0, stream>>>(GLbf, 768, 0, wFU, fus_b, x,
                                               T1, 768, 0, 0, 768, 768, 0);
  ln_f32<<<dim3(512), blk, 0, stream>>>(T1, glce_g, glce_bb, X1);

  // --- bidirectional mamba ---
  ln_bf16<<<dim3(512), blk, 0, stream>>>(X1, ssm_g, ssm_bb, XNbf);
  for (int dir = 0; dir < 2; ++dir) {
    int flip = dir;
    gemm_mx<0><<<dim3(16 * 24), blk, 0, stream>>>(XNbf, 768, flip, wIN[dir], nullptr, nullptr,
                                                  XIZ, 3072, 0, 0, 3072, 768, 0);
    mamba_conv_f32<<<dim3(M * 1536 / 256), blk, 0, stream>>>(XIZ, cw[dir], cb[dir], XC);
    xp_part<<<dim3(32, XP_KSPLIT), blk, 0, stream>>>(XC, xp_w[dir], PART);
    xp_reduce<<<dim3(M * 80 / 256), blk, 0, stream>>>(PART, DBC);
    gemm_f32<<<dim3(24, 32), blk, 0, stream>>>(DBC, 80, 0, dt_w[dir], dt_b[dir], nullptr,
                                               DELTA, 1536, 0, 0, 1536, 48, 1, 0);
    mamba_scan_part<<<dim3(3072), blk, 0, stream>>>(DBC, DELTA, XC, A_log[dir], SS, PP);
    mamba_scan_comb<<<dim3(192), blk, 0, stream>>>(SS, PP, HI);
    mamba_scan_fin<<<dim3(3072), blk, 0, stream>>>(DBC, DELTA, XC, XIZ, A_log[dir],
                                                   Dp[dir], HI, YGbf);
    gemm_mx<0><<<dim3(16 * 6), blk, 0, stream>>>(YGbf, 1536, 0, wOUT[dir], nullptr, nullptr,
                                                 YFB[dir], 768, 0, flip, 768, 1536, 0);
  }
  add3_f32<<<dim3(M * 768 / 256), blk, 0, stream>>>(X1, YF, YB, X2);

  // --- FFN ---
  ln_bf16<<<dim3(512), blk, 0, stream>>>(X2, ffn_g, ffn_bb, XNbf);
  gemm_mx<1><<<dim3(16 * 24), blk, 0, stream>>>(XNbf, 768, 0, wGA, nullptr, nullptr,
                                                GUbf, 3072, 0, 0, 3072, 768, 2);
  gemm_mx<2><<<dim3(16 * 24), blk, 0, stream>>>(XNbf, 768, 0, wUP, nullptr, nullptr,
                                                GUbf, 3072, 0, 0, 3072, 768, 0);
  gemm_mx<0><<<dim3(16 * 6), blk, 0, stream>>>(GUbf, 3072, 0, wDN, nullptr, X2,
                                               (float*)d_out, 768, 0, 0, 768, 3072, 0);
}

// Round 8
// 745.865 us; speedup vs baseline: 1.7811x; 1.0701x over previous
//
#include <hip/hip_runtime.h>
#include <math.h>

#define LSEQ 1024
#define DMODEL 768
#define NHEAD 8
#define HDIM 96
#define DI_ 1536
#define NST 16
#define DTR_ 48
#define FF_ 3072

typedef unsigned short u16;
typedef __attribute__((ext_vector_type(8))) short short8;
typedef __attribute__((ext_vector_type(4))) short short4_t;
typedef __attribute__((ext_vector_type(4))) float f32x4;

__device__ inline short f2bf(float f) {
  unsigned u = __builtin_bit_cast(unsigned, f);
  unsigned r = u + 0x7FFFu + ((u >> 16) & 1u);   // round-to-nearest-even
  return (short)(r >> 16);
}
__device__ inline float bf2f(u16 b) {
  return __builtin_bit_cast(float, (unsigned)b << 16);
}

// ---------------------------------------------------------------------------
// fp32 -> bf16 conversion (weights / x), 4 elems per thread
// ---------------------------------------------------------------------------
__global__ __launch_bounds__(256) void cvt_bf16(const float* __restrict__ s,
                                                u16* __restrict__ d, int n)
{
  int i = (blockIdx.x * 256 + threadIdx.x) * 4;
  if (i >= n) return;
  float4 v = *(const float4*)(s + i);
  *(short4_t*)(d + i) = short4_t{f2bf(v.x), f2bf(v.y), f2bf(v.z), f2bf(v.w)};
}

// ---------------------------------------------------------------------------
// bf16 MFMA GEMM, tile 128x128, BK=64, 4 waves (64x64 quadrant each).
// Register-prefetch pipelined; XOR-swizzled LDS; grouped block order.
// OUTMODE: 0 = f32 store (+optional residual), 1 = bf16 store, 2 = bf16 *=
// ---------------------------------------------------------------------------
template<int OUTMODE>
__global__ __launch_bounds__(256) void gemm_mx(
    const u16* __restrict__ A, int lda, int flipA,
    const u16* __restrict__ W,
    const float* __restrict__ bias,
    const float* __restrict__ residual,
    void* __restrict__ Cv, int ldc, int colOff, int flipC,
    int Ncols, int Kd, int act)
{
  __shared__ u16 As[128 * 64];
  __shared__ u16 Bs[128 * 64];

  const int ncl = Ncols >> 7;
  const int ppg = 4 * ncl;
  const int rm = (blockIdx.x / ppg) * 4 + (blockIdx.x % ppg) % 4;
  const int cn = (blockIdx.x % ppg) / 4;
  const int row0 = rm << 7, col0 = cn << 7;

  const int tid = threadIdx.x;
  const int w = tid >> 6, lane = tid & 63;
  const int m16 = lane & 15, kg = lane >> 4;
  const int wr = w >> 1, wc = w & 1;

  const int sr = tid >> 3;
  const int scg = tid & 7;
  const u16* aptr[4];
  const u16* wptr[4];
  int wof[4];
  #pragma unroll
  for (int u = 0; u < 4; ++u) {
    int gm = row0 + u * 32 + sr;
    int bb = gm >> 10, ll = gm & 1023;
    if (flipA) ll = 1023 - ll;
    aptr[u] = A + (size_t)(bb * 1024 + ll) * lda + scg * 8;
    wptr[u] = W + (size_t)(col0 + u * 32 + sr) * Kd + scg * 8;
    int r = u * 32 + sr;
    wof[u] = r * 64 + ((scg ^ (r & 7)) << 3);
  }

  f32x4 acc[4][4] = {};

  short8 ra[4], rw[4];
  #pragma unroll
  for (int u = 0; u < 4; ++u) {
    ra[u] = *(const short8*)(aptr[u]);
    rw[u] = *(const short8*)(wptr[u]);
  }

  const int nK = Kd >> 6;
  for (int kt = 0; kt < nK; ++kt) {
    __syncthreads();
    #pragma unroll
    for (int u = 0; u < 4; ++u) {
      *(short8*)&As[wof[u]] = ra[u];
      *(short8*)&Bs[wof[u]] = rw[u];
    }
    __syncthreads();
    if (kt + 1 < nK) {
      int ko = (kt + 1) << 6;
      #pragma unroll
      for (int u = 0; u < 4; ++u) {
        ra[u] = *(const short8*)(aptr[u] + ko);
        rw[u] = *(const short8*)(wptr[u] + ko);
      }
    }
    #pragma unroll
    for (int ks = 0; ks < 2; ++ks) {
      short8 af[4], bf[4];
      #pragma unroll
      for (int mi = 0; mi < 4; ++mi) {
        int r = wr * 64 + mi * 16 + m16;
        int cg = (ks * 4 + kg) ^ (r & 7);
        af[mi] = *(const short8*)&As[r * 64 + cg * 8];
      }
      #pragma unroll
      for (int ni = 0; ni < 4; ++ni) {
        int r = wc * 64 + ni * 16 + m16;
        int cg = (ks * 4 + kg) ^ (r & 7);
        bf[ni] = *(const short8*)&Bs[r * 64 + cg * 8];
      }
      #pragma unroll
      for (int mi = 0; mi < 4; ++mi)
        #pragma unroll
        for (int ni = 0; ni < 4; ++ni)
          acc[mi][ni] = __builtin_amdgcn_mfma_f32_16x16x32_bf16(af[mi], bf[ni],
                                                                acc[mi][ni], 0, 0, 0);
    }
  }

  #pragma unroll
  for (int ni = 0; ni < 4; ++ni) {
    int gn = col0 + wc * 64 + ni * 16 + m16;
    float bv = bias ? bias[gn] : 0.f;
    #pragma unroll
    for (int mi = 0; mi < 4; ++mi) {
      #pragma unroll
      for (int r = 0; r < 4; ++r) {
        int gm = row0 + wr * 64 + mi * 16 + (kg << 2) + r;
        int bb = gm >> 10, ll = gm & 1023;
        if (flipC) ll = 1023 - ll;
        float v = acc[mi][ni][r] + bv;
        if (act == 1) v = fmaxf(v, 0.f) + log1pf(__expf(-fabsf(v)));   // softplus
        else if (act == 2) v = v / (1.f + __expf(-v));                 // silu
        size_t idx = (size_t)(bb * 1024 + ll) * ldc + colOff + gn;
        if (OUTMODE == 0) {
          float* C = (float*)Cv;
          C[idx] = residual ? residual[idx] + v : v;
        } else if (OUTMODE == 1) {
          ((u16*)Cv)[idx] = (u16)f2bf(v);
        } else {
          u16* C = (u16*)Cv;
          C[idx] = (u16)f2bf(bf2f(C[idx]) * v);
        }
      }
    }
  }
}

// ---------------------------------------------------------------------------
// fp32 GEMM (kept for the dt projection: K=48)
// ---------------------------------------------------------------------------
__global__ __launch_bounds__(256) void gemm_f32(
    const float* __restrict__ A, int lda, int flipA,
    const float* __restrict__ W,
    const float* __restrict__ bias,
    const float* __restrict__ residual,
    float* __restrict__ C, int ldc, int colOff, int flipC,
    int Ncols, int Kd, int act, int mulC)
{
  __shared__ float As[16][65];
  __shared__ float Bs[16][65];
  const int row0 = blockIdx.y * 64, col0 = blockIdx.x * 64;
  const int tid = threadIdx.x;
  const int tx = tid & 15, ty = tid >> 4;
  float acc[4][4] = {};
  const int lm = tid >> 2;
  const int lk = (tid & 3) << 2;
  int gmL = row0 + lm;
  int bbL = gmL >> 10, llL = gmL & 1023;
  if (flipA) llL = LSEQ - 1 - llL;
  const float* arow = A + (size_t)(bbL * LSEQ + llL) * lda;
  int gnL = col0 + lm;
  const bool wvalid = (gnL < Ncols);
  const float* wrow = W + (size_t)(wvalid ? gnL : 0) * Kd;

  for (int k0 = 0; k0 < Kd; k0 += 16) {
    #pragma unroll
    for (int u = 0; u < 4; ++u) {
      int kkk = k0 + lk + u;
      bool kin = (kkk < Kd);
      As[lk + u][lm] = kin ? arow[kkk] : 0.f;
      Bs[lk + u][lm] = (kin && wvalid) ? wrow[kkk] : 0.f;
    }
    __syncthreads();
    #pragma unroll
    for (int kkk = 0; kkk < 16; ++kkk) {
      float a[4], bv[4];
      #pragma unroll
      for (int i = 0; i < 4; ++i) a[i] = As[kkk][(ty << 2) + i];
      #pragma unroll
      for (int j = 0; j < 4; ++j) bv[j] = Bs[kkk][(tx << 2) + j];
      #pragma unroll
      for (int i = 0; i < 4; ++i)
        #pragma unroll
        for (int j = 0; j < 4; ++j)
          acc[i][j] = fmaf(a[i], bv[j], acc[i][j]);
    }
    __syncthreads();
  }

  #pragma unroll
  for (int i = 0; i < 4; ++i) {
    int gm = row0 + (ty << 2) + i;
    int bb = gm >> 10, ll = gm & 1023;
    if (flipC) ll = LSEQ - 1 - ll;
    size_t base = (size_t)(bb * LSEQ + ll) * ldc + colOff;
    #pragma unroll
    for (int j = 0; j < 4; ++j) {
      int gn = col0 + (tx << 2) + j;
      if (gn >= Ncols) continue;
      float v = acc[i][j];
      if (bias) v += bias[gn];
      if (act == 1) v = fmaxf(v, 0.f) + log1pf(__expf(-fabsf(v)));
      else if (act == 2) v = v / (1.f + __expf(-v));
      size_t idx = base + gn;
      if (mulC) C[idx] *= v;
      else if (residual) C[idx] = residual[idx] + v;
      else C[idx] = v;
    }
  }
}

// ---------------------------------------------------------------------------
// Split-K fp32 GEMM for the skinny xp projection (M=2048, N=80, K=1536).
// ---------------------------------------------------------------------------
#define XP_KSPLIT 8
#define XP_KCH 192
__global__ __launch_bounds__(256) void xp_part(
    const float* __restrict__ A, const float* __restrict__ W,
    float* __restrict__ PART)
{
  __shared__ float As[64][34];
  __shared__ float Ws[80][34];
  const int tid = threadIdx.x;
  const int row0 = blockIdx.x * 64;
  const int kbase = blockIdx.y * XP_KCH;
  const int ty = tid >> 4, tx = tid & 15;

  float acc[4][5] = {};

  for (int ch = 0; ch < XP_KCH; ch += 32) {
    const int gk = kbase + ch;
    __syncthreads();
    #pragma unroll
    for (int u = 0; u < 2; ++u) {
      int i = tid + u * 256;
      int r = i >> 3, k4 = (i & 7) << 2;
      *(float4*)&As[r][k4] = *(const float4*)&A[(size_t)(row0 + r) * 1536 + gk + k4];
    }
    #pragma unroll
    for (int u = 0; u < 3; ++u) {
      int j = tid + u * 256;
      if (j < 640) {
        int c = j >> 3, k4 = (j & 7) << 2;
        *(float4*)&Ws[c][k4] = *(const float4*)&W[(size_t)c * 1536 + gk + k4];
      }
    }
    __syncthreads();
    #pragma unroll
    for (int k = 0; k < 32; k += 2) {
      float2 a2[4], w2[5];
      #pragma unroll
      for (int i = 0; i < 4; ++i) a2[i] = *(const float2*)&As[ty + 16 * i][k];
      #pragma unroll
      for (int j = 0; j < 5; ++j) w2[j] = *(const float2*)&Ws[tx + 16 * j][k];
      #pragma unroll
      for (int i = 0; i < 4; ++i)
        #pragma unroll
        for (int j = 0; j < 5; ++j) {
          acc[i][j] = fmaf(a2[i].x, w2[j].x, acc[i][j]);
          acc[i][j] = fmaf(a2[i].y, w2[j].y, acc[i][j]);
        }
    }
  }

  float* pbase = PART + (size_t)blockIdx.y * 2048 * 80;
  #pragma unroll
  for (int i = 0; i < 4; ++i) {
    int gr = row0 + ty + 16 * i;
    #pragma unroll
    for (int j = 0; j < 5; ++j)
      pbase[(size_t)gr * 80 + tx + 16 * j] = acc[i][j];
  }
}

__global__ __launch_bounds__(256) void xp_reduce(
    const float* __restrict__ PART, float* __restrict__ DBC)
{
  int t = blockIdx.x * 256 + threadIdx.x;
  float s = 0.f;
  #pragma unroll
  for (int ks = 0; ks < XP_KSPLIT; ++ks)
    s += PART[(size_t)ks * 2048 * 80 + t];
  DBC[t] = s;
}

// ---------------------------------------------------------------------------
// MFMA flash attention. One block = one (b,h) x 64 q rows; 4 waves x 16 rows.
// ---------------------------------------------------------------------------
__global__ __launch_bounds__(256) void attn_mfma(const float* __restrict__ qkv,
                                                 u16* __restrict__ o)
{
  __shared__ short Ks[64][104];
  __shared__ short Vt[96][72];
  __shared__ short Ps[4][16][72];

  const int bh = blockIdx.y;
  const int b_ = bh >> 3, h = bh & 7;
  const int q0 = blockIdx.x * 64;
  const int tid = threadIdx.x;
  const int w = tid >> 6, lane = tid & 63;
  const int m16 = lane & 15, g4 = lane >> 4;

  const float sc2 = 0.10206207261596577f * 1.4426950408889634f;

  short8 qf[3];
  {
    const float* qrow = qkv + ((size_t)(b_ * LSEQ) + q0 + w * 16 + m16) * 2304 + h * HDIM;
    #pragma unroll
    for (int c = 0; c < 3; ++c) {
      float4 v0 = *(const float4*)(qrow + c * 32 + g4 * 8);
      float4 v1 = *(const float4*)(qrow + c * 32 + g4 * 8 + 4);
      qf[c] = short8{f2bf(v0.x), f2bf(v0.y), f2bf(v0.z), f2bf(v0.w),
                     f2bf(v1.x), f2bf(v1.y), f2bf(v1.z), f2bf(v1.w)};
    }
  }

  float m_run[4], l_run[4];
  #pragma unroll
  for (int r = 0; r < 4; ++r) { m_run[r] = -INFINITY; l_run[r] = 0.f; }
  f32x4 oacc[6];
  #pragma unroll
  for (int ct = 0; ct < 6; ++ct) oacc[ct] = (f32x4)(0.f);

  const int kr = tid >> 2;
  const int cc = (tid & 3) * 24;

  for (int t = 0; t < LSEQ / 64; ++t) {
    const int k0 = t * 64;
    __syncthreads();
    {
      const float* kp = qkv + ((size_t)(b_ * LSEQ) + k0 + kr) * 2304 + DMODEL + h * HDIM + cc;
      const float* vp = kp + DMODEL;
      #pragma unroll
      for (int u = 0; u < 6; ++u) {
        float4 kv = *(const float4*)(kp + u * 4);
        *(short4_t*)&Ks[kr][cc + u * 4] =
            short4_t{f2bf(kv.x), f2bf(kv.y), f2bf(kv.z), f2bf(kv.w)};
        float4 vv = *(const float4*)(vp + u * 4);
        Vt[cc + u * 4 + 0][kr] = f2bf(vv.x);
        Vt[cc + u * 4 + 1][kr] = f2bf(vv.y);
        Vt[cc + u * 4 + 2][kr] = f2bf(vv.z);
        Vt[cc + u * 4 + 3][kr] = f2bf(vv.w);
      }
    }
    __syncthreads();

    f32x4 sacc[4];
    #pragma unroll
    for (int kt = 0; kt < 4; ++kt) sacc[kt] = (f32x4)(0.f);
    #pragma unroll
    for (int c = 0; c < 3; ++c) {
      #pragma unroll
      for (int kt = 0; kt < 4; ++kt) {
        short8 bfrag = *(const short8*)&Ks[kt * 16 + m16][c * 32 + g4 * 8];
        sacc[kt] = __builtin_amdgcn_mfma_f32_16x16x32_bf16(qf[c], bfrag, sacc[kt], 0, 0, 0);
      }
    }

    #pragma unroll
    for (int r = 0; r < 4; ++r) {
      float s0 = sacc[0][r] * sc2, s1 = sacc[1][r] * sc2;
      float s2v = sacc[2][r] * sc2, s3 = sacc[3][r] * sc2;
      float mv = fmaxf(fmaxf(s0, s1), fmaxf(s2v, s3));
      mv = fmaxf(mv, __shfl_xor(mv, 1));
      mv = fmaxf(mv, __shfl_xor(mv, 2));
      mv = fmaxf(mv, __shfl_xor(mv, 4));
      mv = fmaxf(mv, __shfl_xor(mv, 8));
      float mnew = fmaxf(m_run[r], mv);
      float scale = exp2f(m_run[r] - mnew);
      float p0 = exp2f(s0 - mnew), p1 = exp2f(s1 - mnew);
      float p2 = exp2f(s2v - mnew), p3 = exp2f(s3 - mnew);
      short* pr = &Ps[w][g4 * 4 + r][m16];
      pr[0]  = f2bf(p0);
      pr[16] = f2bf(p1);
      pr[32] = f2bf(p2);
      pr[48] = f2bf(p3);
      float ps = p0 + p1 + p2 + p3;
      ps += __shfl_xor(ps, 1);
      ps += __shfl_xor(ps, 2);
      ps += __shfl_xor(ps, 4);
      ps += __shfl_xor(ps, 8);
      l_run[r] = l_run[r] * scale + ps;
      m_run[r] = mnew;
      #pragma unroll
      for (int ct = 0; ct < 6; ++ct) oacc[ct][r] *= scale;
    }

    #pragma unroll
    for (int kc = 0; kc < 2; ++kc) {
      short8 pa = *(const short8*)&Ps[w][m16][kc * 32 + g4 * 8];
      #pragma unroll
      for (int ct = 0; ct < 6; ++ct) {
        short8 vb = *(const short8*)&Vt[ct * 16 + m16][kc * 32 + g4 * 8];
        oacc[ct] = __builtin_amdgcn_mfma_f32_16x16x32_bf16(pa, vb, oacc[ct], 0, 0, 0);
      }
    }
  }

  #pragma unroll
  for (int r = 0; r < 4; ++r) {
    float inv = 1.f / l_run[r];
    u16* orow = o + ((size_t)(b_ * LSEQ) + q0 + w * 16 + g4 * 4 + r) * DMODEL + h * HDIM;
    #pragma unroll
    for (int ct = 0; ct < 6; ++ct)
      orow[ct * 16 + m16] = (u16)f2bf(oacc[ct][r] * inv);
  }
}

// ---------------------------------------------------------------------------
// GLCE convs (kernels 3/5/7, 3 in-ch per out-ch, exact gelu) -> bf16
// ---------------------------------------------------------------------------
__global__ __launch_bounds__(256) void glce_conv(
    const float* __restrict__ x,
    const float* __restrict__ w3, const float* __restrict__ b3,
    const float* __restrict__ w5, const float* __restrict__ b5,
    const float* __restrict__ w7, const float* __restrict__ b7,
    u16* __restrict__ loc)
{
  int idx = blockIdx.x * 256 + threadIdx.x;
  int c = idx % DMODEL;
  int bl = idx / DMODEL;
  int l = bl & 1023, b_ = bl >> 10;
  int cs = c >> 8, ch = c & 255;
  const float* wp; float bias; int kt, pad;
  if (cs == 0)      { wp = w3 + ch * 9;  bias = b3[ch]; kt = 3; pad = 1; }
  else if (cs == 1) { wp = w5 + ch * 15; bias = b5[ch]; kt = 5; pad = 2; }
  else              { wp = w7 + ch * 21; bias = b7[ch]; kt = 7; pad = 3; }
  float acc = bias;
  const float* xb = x + (size_t)(b_ * LSEQ) * DMODEL;
  for (int i = 0; i < 3; ++i) {
    int d = 3 * ch + i;
    for (int t = 0; t < kt; ++t) {
      int ls = l - pad + t;
      if (ls >= 0 && ls < LSEQ)
        acc = fmaf(xb[(size_t)ls * DMODEL + d], wp[i * kt + t], acc);
    }
  }
  loc[idx] = (u16)f2bf(0.5f * acc * (1.f + erff(acc * 0.7071067811865475f)));
}

// ---------------------------------------------------------------------------
// Mamba depthwise causal conv (K=4) + silu
// ---------------------------------------------------------------------------
__global__ __launch_bounds__(256) void mamba_conv_f32(
    const float* __restrict__ xiz, const float* __restrict__ cw,
    const float* __restrict__ cb, float* __restrict__ xc)
{
  int idx = blockIdx.x * 256 + threadIdx.x;
  int d = idx % DI_;
  int bl = idx / DI_;
  int l = bl & 1023, b_ = bl >> 10;
  const float* w = cw + d * 4;
  float acc = cb[d];
  #pragma unroll
  for (int t = 0; t < 4; ++t) {
    int ls = l - 3 + t;
    if (ls >= 0)
      acc = fmaf(xiz[((size_t)(b_ * LSEQ + ls)) * 3072 + d], w[t], acc);
  }
  xc[idx] = acc / (1.f + __expf(-acc));
}

// ---------------------------------------------------------------------------
// Chunked selective scan, 4 states per thread. CHUNK=64, NCHUNK=16.
// Block = 64 d's x 1 chunk; thread (dl = tid>>2, ng = tid&3) owns n = 4ng..4ng+3.
// Grid: 2 * 24 * 16 = 768 blocks. Steps staged 32 at a time in LDS.
// Index layout for S/P/HI: ((b*1536+d)*16 + chunk)*16 + n.
// ---------------------------------------------------------------------------
__global__ __launch_bounds__(256) void mamba_scan_part(
    const float* __restrict__ dbc, const float* __restrict__ delta,
    const float* __restrict__ xc, const float* __restrict__ A_log,
    float* __restrict__ SS, float* __restrict__ PP)
{
  const int bc = blockIdx.x;
  const int b_ = bc / 384;
  const int rem = bc % 384;
  const int d0 = (rem >> 4) * 64;
  const int ck = rem & 15;
  const int tid = threadIdx.x;
  const int dl = tid >> 2, ng = tid & 3;
  const int d = d0 + dl;

  float4 a2;
  {
    float4 al = *(const float4*)&A_log[d * 16 + ng * 4];
    a2.x = -__expf(al.x) * 1.4426950408889634f;
    a2.y = -__expf(al.y) * 1.4426950408889634f;
    a2.z = -__expf(al.z) * 1.4426950408889634f;
    a2.w = -__expf(al.w) * 1.4426950408889634f;
  }

  __shared__ float sdel[32][64];
  __shared__ float sxc[32][64];
  __shared__ float sB[32][16];
  const size_t rowb = (size_t)b_ * LSEQ + ck * 64;

  float4 h = {0.f, 0.f, 0.f, 0.f};
  float sumd = 0.f;

  for (int half = 0; half < 2; ++half) {
    const int lbase = half * 32;
    __syncthreads();
    #pragma unroll
    for (int k = 0; k < 8; ++k) {
      int i = tid + k * 256;
      int lc = i >> 6, c = i & 63;
      size_t row = rowb + lbase + lc;
      sdel[lc][c] = delta[row * 1536 + d0 + c];
      sxc[lc][c]  = xc[row * 1536 + d0 + c];
    }
    #pragma unroll
    for (int k = 0; k < 2; ++k) {
      int i = tid + k * 256;
      int lc = i >> 4, n = i & 15;
      sB[lc][n] = dbc[(rowb + lbase + lc) * 80 + 48 + n];
    }
    __syncthreads();
    for (int lc = 0; lc < 32; ++lc) {
      float dlv = sdel[lc][dl];
      float xv  = sxc[lc][dl];
      float dx  = dlv * xv;
      float4 B4 = *(const float4*)&sB[lc][ng * 4];
      h.x = fmaf(exp2f(dlv * a2.x), h.x, dx * B4.x);
      h.y = fmaf(exp2f(dlv * a2.y), h.y, dx * B4.y);
      h.z = fmaf(exp2f(dlv * a2.z), h.z, dx * B4.z);
      h.w = fmaf(exp2f(dlv * a2.w), h.w, dx * B4.w);
      sumd += dlv;
    }
  }

  size_t idx = (((size_t)b_ * 1536 + d) * 16 + ck) * 16 + ng * 4;
  *(float4*)&SS[idx] = h;
  float4 pp;
  pp.x = exp2f(a2.x * sumd);
  pp.y = exp2f(a2.y * sumd);
  pp.z = exp2f(a2.z * sumd);
  pp.w = exp2f(a2.w * sumd);
  *(float4*)&PP[idx] = pp;
}

__global__ __launch_bounds__(256) void mamba_scan_comb(
    const float* __restrict__ SS, const float* __restrict__ PP,
    float* __restrict__ HI)
{
  int t = blockIdx.x * 256 + threadIdx.x;
  size_t base = (size_t)(t >> 4) * 256 + (t & 15);
  float run = 0.f;
  #pragma unroll
  for (int c = 0; c < 16; ++c) {
    size_t idx = base + c * 16;
    HI[idx] = run;
    run = fmaf(PP[idx], run, SS[idx]);
  }
}

__global__ __launch_bounds__(256) void mamba_scan_fin(
    const float* __restrict__ dbc, const float* __restrict__ delta,
    const float* __restrict__ xc, const float* __restrict__ xiz,
    const float* __restrict__ A_log, const float* __restrict__ Dp,
    const float* __restrict__ HI, u16* __restrict__ yg)
{
  const int bc = blockIdx.x;
  const int b_ = bc / 384;
  const int rem = bc % 384;
  const int d0 = (rem >> 4) * 64;
  const int ck = rem & 15;
  const int tid = threadIdx.x;
  const int dl = tid >> 2, ng = tid & 3;
  const int d = d0 + dl;

  float4 a2;
  {
    float4 al = *(const float4*)&A_log[d * 16 + ng * 4];
    a2.x = -__expf(al.x) * 1.4426950408889634f;
    a2.y = -__expf(al.y) * 1.4426950408889634f;
    a2.z = -__expf(al.z) * 1.4426950408889634f;
    a2.w = -__expf(al.w) * 1.4426950408889634f;
  }
  const float dv = Dp[d];

  __shared__ float sdel[32][64];
  __shared__ float sxc[32][64];
  __shared__ float sz[32][64];
  __shared__ float sB[32][16];
  __shared__ float sC[32][16];
  __shared__ float sy[32][64];
  const size_t rowb = (size_t)b_ * LSEQ + ck * 64;

  float4 h = *(const float4*)&HI[(((size_t)b_ * 1536 + d) * 16 + ck) * 16 + ng * 4];

  for (int half = 0; half < 2; ++half) {
    const int lbase = half * 32;
    __syncthreads();   // prior half's sy fully drained
    #pragma unroll
    for (int k = 0; k < 8; ++k) {
      int i = tid + k * 256;
      int lc = i >> 6, c = i & 63;
      size_t row = rowb + lbase + lc;
      sdel[lc][c] = delta[row * 1536 + d0 + c];
      sxc[lc][c]  = xc[row * 1536 + d0 + c];
      sz[lc][c]   = xiz[row * 3072 + 1536 + d0 + c];
    }
    #pragma unroll
    for (int k = 0; k < 2; ++k) {
      int i = tid + k * 256;
      int lc = i >> 4, n = i & 15;
      size_t row = rowb + lbase + lc;
      sB[lc][n] = dbc[row * 80 + 48 + n];
      sC[lc][n] = dbc[row * 80 + 64 + n];
    }
    __syncthreads();
    for (int lc = 0; lc < 32; ++lc) {
      float dlv = sdel[lc][dl];
      float xv  = sxc[lc][dl];
      float dx  = dlv * xv;
      float4 B4 = *(const float4*)&sB[lc][ng * 4];
      float4 C4 = *(const float4*)&sC[lc][ng * 4];
      h.x = fmaf(exp2f(dlv * a2.x), h.x, dx * B4.x);
      h.y = fmaf(exp2f(dlv * a2.y), h.y, dx * B4.y);
      h.z = fmaf(exp2f(dlv * a2.z), h.z, dx * B4.z);
      h.w = fmaf(exp2f(dlv * a2.w), h.w, dx * B4.w);
      float p = fmaf(h.x, C4.x, fmaf(h.y, C4.y, fmaf(h.z, C4.z, h.w * C4.w)));
      p += __shfl_xor(p, 1);
      p += __shfl_xor(p, 2);
      if (ng == 0) {
        float zv = sz[lc][dl];
        float y = p + xv * dv;
        sy[lc][dl] = y * (zv / (1.f + __expf(-zv)));
      }
    }
    __syncthreads();
    #pragma unroll
    for (int k = 0; k < 8; ++k) {
      int i = tid + k * 256;
      int lc = i >> 6, c = i & 63;
      yg[(rowb + lbase + lc) * 1536 + d0 + c] = (u16)f2bf(sy[lc][c]);
    }
  }
}

// ---------------------------------------------------------------------------
// LayerNorm over last dim (768): fp32-out and bf16-out variants
// ---------------------------------------------------------------------------
__global__ __launch_bounds__(256) void ln_f32(
    const float* __restrict__ in, const float* __restrict__ g,
    const float* __restrict__ b, float* __restrict__ out)
{
  int row = blockIdx.x * 4 + (threadIdx.x >> 6);
  int lane = threadIdx.x & 63;
  const float* xr = in + (size_t)row * DMODEL;
  float v[12];
  float s = 0.f, s2 = 0.f;
  #pragma unroll
  for (int i = 0; i < 12; ++i) {
    float t = xr[i * 64 + lane];
    v[i] = t; s += t; s2 = fmaf(t, t, s2);
  }
  #pragma unroll
  for (int off = 1; off < 64; off <<= 1) {
    s += __shfl_xor(s, off);
    s2 += __shfl_xor(s2, off);
  }
  float mean = s * (1.f / 768.f);
  float var = s2 * (1.f / 768.f) - mean * mean;
  float inv = rsqrtf(var + 1e-5f);
  float* orow = out + (size_t)row * DMODEL;
  #pragma unroll
  for (int i = 0; i < 12; ++i) {
    int c = i * 64 + lane;
    orow[c] = (v[i] - mean) * inv * g[c] + b[c];
  }
}

__global__ __launch_bounds__(256) void ln_bf16(
    const float* __restrict__ in, const float* __restrict__ g,
    const float* __restrict__ b, u16* __restrict__ out)
{
  int row = blockIdx.x * 4 + (threadIdx.x >> 6);
  int lane = threadIdx.x & 63;
  const float* xr = in + (size_t)row * DMODEL;
  float v[12];
  float s = 0.f, s2 = 0.f;
  #pragma unroll
  for (int i = 0; i < 12; ++i) {
    float t = xr[i * 64 + lane];
    v[i] = t; s += t; s2 = fmaf(t, t, s2);
  }
  #pragma unroll
  for (int off = 1; off < 64; off <<= 1) {
    s += __shfl_xor(s, off);
    s2 += __shfl_xor(s2, off);
  }
  float mean = s * (1.f / 768.f);
  float var = s2 * (1.f / 768.f) - mean * mean;
  float inv = rsqrtf(var + 1e-5f);
  u16* orow = out + (size_t)row * DMODEL;
  #pragma unroll
  for (int i = 0; i < 12; ++i) {
    int c = i * 64 + lane;
    orow[c] = (u16)f2bf((v[i] - mean) * inv * g[c] + b[c]);
  }
}

__global__ __launch_bounds__(256) void add3_f32(
    const float* __restrict__ a, const float* __restrict__ b,
    const float* __restrict__ c, float* __restrict__ o)
{
  int i = blockIdx.x * 256 + threadIdx.x;
  o[i] = a[i] + b[i] + c[i];
}

// ---------------------------------------------------------------------------
extern "C" void kernel_launch(void* const* d_in, const int* in_sizes, int n_in,
                              void* d_out, int out_size, void* d_ws, size_t ws_size,
                              hipStream_t stream)
{
  (void)in_sizes; (void)n_in; (void)out_size; (void)ws_size;
  const float* x         = (const float*)d_in[0];
  const float* qkv_w     = (const float*)d_in[1];
  const float* qkv_b     = (const float*)d_in[2];
  const float* att_out_w = (const float*)d_in[3];
  const float* att_out_b = (const float*)d_in[4];
  const float* conv3_w   = (const float*)d_in[5];
  const float* conv3_b   = (const float*)d_in[6];
  const float* conv5_w   = (const float*)d_in[7];
  const float* conv5_b   = (const float*)d_in[8];
  const float* conv7_w   = (const float*)d_in[9];
  const float* conv7_b   = (const float*)d_in[10];
  const float* gproj_w   = (const float*)d_in[11];
  const float* gproj_b   = (const float*)d_in[12];
  const float* lproj_w   = (const float*)d_in[13];
  const float* lproj_b   = (const float*)d_in[14];
  const float* fus_w     = (const float*)d_in[15];
  const float* fus_b     = (const float*)d_in[16];
  const float* glce_g    = (const float*)d_in[17];
  const float* glce_bb   = (const float*)d_in[18];
  const float* ssm_g     = (const float*)d_in[19];
  const float* ssm_bb    = (const float*)d_in[20];
  const float* in_w[2]   = {(const float*)d_in[21], (const float*)d_in[30]};
  const float* cw[2]     = {(const float*)d_in[22], (const float*)d_in[31]};
  const float* cb[2]     = {(const float*)d_in[23], (const float*)d_in[32]};
  const float* xp_w[2]   = {(const float*)d_in[24], (const float*)d_in[33]};
  const float* dt_w[2]   = {(const float*)d_in[25], (const float*)d_in[34]};
  const float* dt_b[2]   = {(const float*)d_in[26], (const float*)d_in[35]};
  const float* A_log[2]  = {(const float*)d_in[27], (const float*)d_in[36]};
  const float* Dp[2]     = {(const float*)d_in[28], (const float*)d_in[37]};
  const float* out_w[2]  = {(const float*)d_in[29], (const float*)d_in[38]};
  const float* ffn_g     = (const float*)d_in[39];
  const float* ffn_bb    = (const float*)d_in[40];
  const float* gate_w    = (const float*)d_in[41];
  const float* up_w      = (const float*)d_in[42];
  const float* down_w    = (const float*)d_in[43];

  float* ws = (float*)d_ws;
  size_t off = 0;
  const size_t M = 2048;
  auto take = [&](size_t n) { float* p = ws + off; off += n; return p; };
  auto takeb = [&](size_t n) { u16* p = (u16*)(ws + off); off += (n + 1) / 2; return p; };

  float* QKV   = take(M * 2304);
  float* T1    = take(M * 768);
  float* X1    = take(M * 768);
  float* XIZ   = take(M * 3072);
  float* XC    = take(M * 1536);
  float* DBC   = take(M * 80);
  float* DELTA = take(M * 1536);
  float* YF    = take(M * 768);
  float* YB    = take(M * 768);
  float* X2    = take(M * 768);
  float* SS    = take(2 * 1536 * 16 * 16);
  float* PP    = take(2 * 1536 * 16 * 16);
  float* HI    = take(2 * 1536 * 16 * 16);
  float* PART  = take((size_t)XP_KSPLIT * M * 80);

  u16* Xbf   = takeb(M * 768);
  u16* AObf  = takeb(M * 768);
  u16* AO2bf = takeb(M * 768);
  u16* GLbf  = takeb(M * 768);
  u16* LOCbf = takeb(M * 768);
  u16* XNbf  = takeb(M * 768);
  u16* YGbf  = takeb(M * 1536);
  u16* GUbf  = (u16*)XIZ;            // alias: XIZ fully consumed before FFN

  // bf16 weights
  u16* wQKV  = takeb(2304 * 768);
  u16* wAT   = takeb(768 * 768);
  u16* wGP   = takeb(384 * 768);
  u16* wLP   = takeb(384 * 768);
  u16* wFU   = takeb(768 * 768);
  u16* wIN[2]  = {takeb(3072 * 768), takeb(3072 * 768)};
  u16* wOUT[2] = {takeb(768 * 1536), takeb(768 * 1536)};
  u16* wGA   = takeb(3072 * 768);
  u16* wUP   = takeb(3072 * 768);
  u16* wDN   = takeb(768 * 3072);

  float* YFB[2] = {YF, YB};
  dim3 blk(256);

  // --- weight + input conversions ---
  auto cvt = [&](const float* s, u16* d, int n) {
    cvt_bf16<<<dim3(n / 1024), blk, 0, stream>>>(s, d, n);
  };
  cvt(x, Xbf, M * 768);
  cvt(qkv_w, wQKV, 2304 * 768);
  cvt(att_out_w, wAT, 768 * 768);
  cvt(gproj_w, wGP, 384 * 768);
  cvt(lproj_w, wLP, 384 * 768);
  cvt(fus_w, wFU, 768 * 768);
  cvt(in_w[0], wIN[0], 3072 * 768);
  cvt(in_w[1], wIN[1], 3072 * 768);
  cvt(out_w[0], wOUT[0], 768 * 1536);
  cvt(out_w[1], wOUT[1], 768 * 1536);
  cvt(gate_w, wGA, 3072 * 768);
  cvt(up_w, wUP, 3072 * 768);
  cvt(down_w, wDN, 768 * 3072);

  // --- GLCE branch ---
  gemm_mx<0><<<dim3(16 * 18), blk, 0, stream>>>(Xbf, 768, 0, wQKV, qkv_b, nullptr,
                                                QKV, 2304, 0, 0, 2304, 768, 0);
  attn_mfma<<<dim3(16, 16), blk, 0, stream>>>(QKV, AObf);
  gemm_mx<1><<<dim3(16 * 6), blk, 0, stream>>>(AObf, 768, 0, wAT, att_out_b, nullptr,
                                               AO2bf, 768, 0, 0, 768, 768, 0);
  gemm_mx<1><<<dim3(16 * 3), blk, 0, stream>>>(AO2bf, 768, 0, wGP, gproj_b, nullptr,
                                               GLbf, 768, 0, 0, 384, 768, 0);
  glce_conv<<<dim3(M * 768 / 256), blk, 0, stream>>>(x, conv3_w, conv3_b, conv5_w,
                                                     conv5_b, conv7_w, conv7_b, LOCbf);
  gemm_mx<1><<<dim3(16 * 3), blk, 0, stream>>>(LOCbf, 768, 0, wLP, lproj_b, nullptr,
                                               GLbf, 768, 384, 0, 384, 768, 0);
  gemm_mx<0><<<dim3(16 * 6), blk, 0, stream>>>(GLbf, 768, 0, wFU, fus_b, x,
                                               T1, 768, 0, 0, 768, 768, 0);
  ln_f32<<<dim3(512), blk, 0, stream>>>(T1, glce_g, glce_bb, X1);

  // --- bidirectional mamba ---
  ln_bf16<<<dim3(512), blk, 0, stream>>>(X1, ssm_g, ssm_bb, XNbf);
  for (int dir = 0; dir < 2; ++dir) {
    int flip = dir;
    gemm_mx<0><<<dim3(16 * 24), blk, 0, stream>>>(XNbf, 768, flip, wIN[dir], nullptr, nullptr,
                                                  XIZ, 3072, 0, 0, 3072, 768, 0);
    mamba_conv_f32<<<dim3(M * 1536 / 256), blk, 0, stream>>>(XIZ, cw[dir], cb[dir], XC);
    xp_part<<<dim3(32, XP_KSPLIT), blk, 0, stream>>>(XC, xp_w[dir], PART);
    xp_reduce<<<dim3(M * 80 / 256), blk, 0, stream>>>(PART, DBC);
    gemm_f32<<<dim3(24, 32), blk, 0, stream>>>(DBC, 80, 0, dt_w[dir], dt_b[dir], nullptr,
                                               DELTA, 1536, 0, 0, 1536, 48, 1, 0);
    mamba_scan_part<<<dim3(768), blk, 0, stream>>>(DBC, DELTA, XC, A_log[dir], SS, PP);
    mamba_scan_comb<<<dim3(192), blk, 0, stream>>>(SS, PP, HI);
    mamba_scan_fin<<<dim3(768), blk, 0, stream>>>(DBC, DELTA, XC, XIZ, A_log[dir],
                                                  Dp[dir], HI, YGbf);
    gemm_mx<0><<<dim3(16 * 6), blk, 0, stream>>>(YGbf, 1536, 0, wOUT[dir], nullptr, nullptr,
                                                 YFB[dir], 768, 0, flip, 768, 1536, 0);
  }
  add3_f32<<<dim3(M * 768 / 256), blk, 0, stream>>>(X1, YF, YB, X2);

  // --- FFN ---
  ln_bf16<<<dim3(512), blk, 0, stream>>>(X2, ffn_g, ffn_bb, XNbf);
  gemm_mx<1><<<dim3(16 * 24), blk, 0, stream>>>(XNbf, 768, 0, wGA, nullptr, nullptr,
                                                GUbf, 3072, 0, 0, 3072, 768, 2);
  gemm_mx<2><<<dim3(16 * 24), blk, 0, stream>>>(XNbf, 768, 0, wUP, nullptr, nullptr,
                                                GUbf, 3072, 0, 0, 3072, 768, 0);
  gemm_mx<0><<<dim3(16 * 6), blk, 0, stream>>>(GUbf, 3072, 0, wDN, nullptr, X2,
                                               (float*)d_out, 768, 0, 0, 768, 3072, 0);
}

// Round 9
// 700.761 us; speedup vs baseline: 1.8957x; 1.0644x over previous
//
#include <hip/hip_runtime.h>
#include <math.h>

#define LSEQ 1024
#define DMODEL 768
#define NHEAD 8
#define HDIM 96
#define DI_ 1536
#define NST 16
#define DTR_ 48
#define FF_ 3072

typedef unsigned short u16;
typedef __attribute__((ext_vector_type(8))) short short8;
typedef __attribute__((ext_vector_type(4))) short short4_t;
typedef __attribute__((ext_vector_type(4))) float f32x4;

__device__ inline short f2bf(float f) {
  unsigned u = __builtin_bit_cast(unsigned, f);
  unsigned r = u + 0x7FFFu + ((u >> 16) & 1u);   // round-to-nearest-even
  return (short)(r >> 16);
}
__device__ inline float bf2f(u16 b) {
  return __builtin_bit_cast(float, (unsigned)b << 16);
}

// ---------------------------------------------------------------------------
// Batched fp32 -> bf16 conversion: one launch for all weights + x.
// Every job's n is a multiple of 1024 (one block = 1024 elems).
// ---------------------------------------------------------------------------
#define NCVT 13
struct CvtJobs {
  const float* s[NCVT];
  u16* d[NCVT];
  int nblk[NCVT];
};
__global__ __launch_bounds__(256) void cvt_batch(CvtJobs j)
{
  int b = blockIdx.x;
  int e = 0;
  while (b >= j.nblk[e]) { b -= j.nblk[e]; ++e; }
  int i = (b * 256 + threadIdx.x) * 4;
  float4 v = *(const float4*)(j.s[e] + i);
  *(short4_t*)(j.d[e] + i) = short4_t{f2bf(v.x), f2bf(v.y), f2bf(v.z), f2bf(v.w)};
}

// ---------------------------------------------------------------------------
// bf16 MFMA GEMM, tile 128x128, BK=64, 4 waves (64x64 quadrant each).
// Register-prefetch pipelined; XOR-swizzled LDS; grouped block order.
// OUTMODE: 0 = f32 store (+optional residual), 1 = bf16 store, 2 = bf16 *=
// ---------------------------------------------------------------------------
template<int OUTMODE>
__global__ __launch_bounds__(256) void gemm_mx(
    const u16* __restrict__ A, int lda, int flipA,
    const u16* __restrict__ W,
    const float* __restrict__ bias,
    const float* __restrict__ residual,
    void* __restrict__ Cv, int ldc, int colOff, int flipC,
    int Ncols, int Kd, int act)
{
  __shared__ u16 As[128 * 64];
  __shared__ u16 Bs[128 * 64];

  const int ncl = Ncols >> 7;
  const int ppg = 4 * ncl;
  const int rm = (blockIdx.x / ppg) * 4 + (blockIdx.x % ppg) % 4;
  const int cn = (blockIdx.x % ppg) / 4;
  const int row0 = rm << 7, col0 = cn << 7;

  const int tid = threadIdx.x;
  const int w = tid >> 6, lane = tid & 63;
  const int m16 = lane & 15, kg = lane >> 4;
  const int wr = w >> 1, wc = w & 1;

  const int sr = tid >> 3;
  const int scg = tid & 7;
  const u16* aptr[4];
  const u16* wptr[4];
  int wof[4];
  #pragma unroll
  for (int u = 0; u < 4; ++u) {
    int gm = row0 + u * 32 + sr;
    int bb = gm >> 10, ll = gm & 1023;
    if (flipA) ll = 1023 - ll;
    aptr[u] = A + (size_t)(bb * 1024 + ll) * lda + scg * 8;
    wptr[u] = W + (size_t)(col0 + u * 32 + sr) * Kd + scg * 8;
    int r = u * 32 + sr;
    wof[u] = r * 64 + ((scg ^ (r & 7)) << 3);
  }

  f32x4 acc[4][4] = {};

  short8 ra[4], rw[4];
  #pragma unroll
  for (int u = 0; u < 4; ++u) {
    ra[u] = *(const short8*)(aptr[u]);
    rw[u] = *(const short8*)(wptr[u]);
  }

  const int nK = Kd >> 6;
  for (int kt = 0; kt < nK; ++kt) {
    __syncthreads();
    #pragma unroll
    for (int u = 0; u < 4; ++u) {
      *(short8*)&As[wof[u]] = ra[u];
      *(short8*)&Bs[wof[u]] = rw[u];
    }
    __syncthreads();
    if (kt + 1 < nK) {
      int ko = (kt + 1) << 6;
      #pragma unroll
      for (int u = 0; u < 4; ++u) {
        ra[u] = *(const short8*)(aptr[u] + ko);
        rw[u] = *(const short8*)(wptr[u] + ko);
      }
    }
    #pragma unroll
    for (int ks = 0; ks < 2; ++ks) {
      short8 af[4], bf[4];
      #pragma unroll
      for (int mi = 0; mi < 4; ++mi) {
        int r = wr * 64 + mi * 16 + m16;
        int cg = (ks * 4 + kg) ^ (r & 7);
        af[mi] = *(const short8*)&As[r * 64 + cg * 8];
      }
      #pragma unroll
      for (int ni = 0; ni < 4; ++ni) {
        int r = wc * 64 + ni * 16 + m16;
        int cg = (ks * 4 + kg) ^ (r & 7);
        bf[ni] = *(const short8*)&Bs[r * 64 + cg * 8];
      }
      #pragma unroll
      for (int mi = 0; mi < 4; ++mi)
        #pragma unroll
        for (int ni = 0; ni < 4; ++ni)
          acc[mi][ni] = __builtin_amdgcn_mfma_f32_16x16x32_bf16(af[mi], bf[ni],
                                                                acc[mi][ni], 0, 0, 0);
    }
  }

  #pragma unroll
  for (int ni = 0; ni < 4; ++ni) {
    int gn = col0 + wc * 64 + ni * 16 + m16;
    float bv = bias ? bias[gn] : 0.f;
    #pragma unroll
    for (int mi = 0; mi < 4; ++mi) {
      #pragma unroll
      for (int r = 0; r < 4; ++r) {
        int gm = row0 + wr * 64 + mi * 16 + (kg << 2) + r;
        int bb = gm >> 10, ll = gm & 1023;
        if (flipC) ll = 1023 - ll;
        float v = acc[mi][ni][r] + bv;
        if (act == 1) v = fmaxf(v, 0.f) + log1pf(__expf(-fabsf(v)));   // softplus
        else if (act == 2) v = v / (1.f + __expf(-v));                 // silu
        size_t idx = (size_t)(bb * 1024 + ll) * ldc + colOff + gn;
        if (OUTMODE == 0) {
          float* C = (float*)Cv;
          C[idx] = residual ? residual[idx] + v : v;
        } else if (OUTMODE == 1) {
          ((u16*)Cv)[idx] = (u16)f2bf(v);
        } else {
          u16* C = (u16*)Cv;
          C[idx] = (u16)f2bf(bf2f(C[idx]) * v);
        }
      }
    }
  }
}

// ---------------------------------------------------------------------------
// fp32 GEMM (kept for the dt projection: K=48)
// ---------------------------------------------------------------------------
__global__ __launch_bounds__(256) void gemm_f32(
    const float* __restrict__ A, int lda, int flipA,
    const float* __restrict__ W,
    const float* __restrict__ bias,
    const float* __restrict__ residual,
    float* __restrict__ C, int ldc, int colOff, int flipC,
    int Ncols, int Kd, int act, int mulC)
{
  __shared__ float As[16][65];
  __shared__ float Bs[16][65];
  const int row0 = blockIdx.y * 64, col0 = blockIdx.x * 64;
  const int tid = threadIdx.x;
  const int tx = tid & 15, ty = tid >> 4;
  float acc[4][4] = {};
  const int lm = tid >> 2;
  const int lk = (tid & 3) << 2;
  int gmL = row0 + lm;
  int bbL = gmL >> 10, llL = gmL & 1023;
  if (flipA) llL = LSEQ - 1 - llL;
  const float* arow = A + (size_t)(bbL * LSEQ + llL) * lda;
  int gnL = col0 + lm;
  const bool wvalid = (gnL < Ncols);
  const float* wrow = W + (size_t)(wvalid ? gnL : 0) * Kd;

  for (int k0 = 0; k0 < Kd; k0 += 16) {
    #pragma unroll
    for (int u = 0; u < 4; ++u) {
      int kkk = k0 + lk + u;
      bool kin = (kkk < Kd);
      As[lk + u][lm] = kin ? arow[kkk] : 0.f;
      Bs[lk + u][lm] = (kin && wvalid) ? wrow[kkk] : 0.f;
    }
    __syncthreads();
    #pragma unroll
    for (int kkk = 0; kkk < 16; ++kkk) {
      float a[4], bv[4];
      #pragma unroll
      for (int i = 0; i < 4; ++i) a[i] = As[kkk][(ty << 2) + i];
      #pragma unroll
      for (int j = 0; j < 4; ++j) bv[j] = Bs[kkk][(tx << 2) + j];
      #pragma unroll
      for (int i = 0; i < 4; ++i)
        #pragma unroll
        for (int j = 0; j < 4; ++j)
          acc[i][j] = fmaf(a[i], bv[j], acc[i][j]);
    }
    __syncthreads();
  }

  #pragma unroll
  for (int i = 0; i < 4; ++i) {
    int gm = row0 + (ty << 2) + i;
    int bb = gm >> 10, ll = gm & 1023;
    if (flipC) ll = LSEQ - 1 - ll;
    size_t base = (size_t)(bb * LSEQ + ll) * ldc + colOff;
    #pragma unroll
    for (int j = 0; j < 4; ++j) {
      int gn = col0 + (tx << 2) + j;
      if (gn >= Ncols) continue;
      float v = acc[i][j];
      if (bias) v += bias[gn];
      if (act == 1) v = fmaxf(v, 0.f) + log1pf(__expf(-fabsf(v)));
      else if (act == 2) v = v / (1.f + __expf(-v));
      size_t idx = base + gn;
      if (mulC) C[idx] *= v;
      else if (residual) C[idx] = residual[idx] + v;
      else C[idx] = v;
    }
  }
}

// ---------------------------------------------------------------------------
// Split-K fp32 GEMM for the skinny xp projection (M=2048, N=80, K=1536).
// ---------------------------------------------------------------------------
#define XP_KSPLIT 8
#define XP_KCH 192
__global__ __launch_bounds__(256) void xp_part(
    const float* __restrict__ A, const float* __restrict__ W,
    float* __restrict__ PART)
{
  __shared__ float As[64][34];
  __shared__ float Ws[80][34];
  const int tid = threadIdx.x;
  const int row0 = blockIdx.x * 64;
  const int kbase = blockIdx.y * XP_KCH;
  const int ty = tid >> 4, tx = tid & 15;

  float acc[4][5] = {};

  for (int ch = 0; ch < XP_KCH; ch += 32) {
    const int gk = kbase + ch;
    __syncthreads();
    #pragma unroll
    for (int u = 0; u < 2; ++u) {
      int i = tid + u * 256;
      int r = i >> 3, k4 = (i & 7) << 2;
      *(float4*)&As[r][k4] = *(const float4*)&A[(size_t)(row0 + r) * 1536 + gk + k4];
    }
    #pragma unroll
    for (int u = 0; u < 3; ++u) {
      int j = tid + u * 256;
      if (j < 640) {
        int c = j >> 3, k4 = (j & 7) << 2;
        *(float4*)&Ws[c][k4] = *(const float4*)&W[(size_t)c * 1536 + gk + k4];
      }
    }
    __syncthreads();
    #pragma unroll
    for (int k = 0; k < 32; k += 2) {
      float2 a2[4], w2[5];
      #pragma unroll
      for (int i = 0; i < 4; ++i) a2[i] = *(const float2*)&As[ty + 16 * i][k];
      #pragma unroll
      for (int j = 0; j < 5; ++j) w2[j] = *(const float2*)&Ws[tx + 16 * j][k];
      #pragma unroll
      for (int i = 0; i < 4; ++i)
        #pragma unroll
        for (int j = 0; j < 5; ++j) {
          acc[i][j] = fmaf(a2[i].x, w2[j].x, acc[i][j]);
          acc[i][j] = fmaf(a2[i].y, w2[j].y, acc[i][j]);
        }
    }
  }

  float* pbase = PART + (size_t)blockIdx.y * 2048 * 80;
  #pragma unroll
  for (int i = 0; i < 4; ++i) {
    int gr = row0 + ty + 16 * i;
    #pragma unroll
    for (int j = 0; j < 5; ++j)
      pbase[(size_t)gr * 80 + tx + 16 * j] = acc[i][j];
  }
}

__global__ __launch_bounds__(256) void xp_reduce(
    const float* __restrict__ PART, float* __restrict__ DBC)
{
  int t = blockIdx.x * 256 + threadIdx.x;
  float s = 0.f;
  #pragma unroll
  for (int ks = 0; ks < XP_KSPLIT; ++ks)
    s += PART[(size_t)ks * 2048 * 80 + t];
  DBC[t] = s;
}

// ---------------------------------------------------------------------------
// MFMA flash attention on bf16 QKV. Grid: 256 linear blocks, bid = q0*16 + bh
// so all 16 q-blocks of one (b,h) share an XCD (bid%8 = bh%8) -> K/V L2-hot.
// ---------------------------------------------------------------------------
__global__ __launch_bounds__(256) void attn_mfma(const u16* __restrict__ qkv,
                                                 u16* __restrict__ o)
{
  __shared__ short Ks[64][104];
  __shared__ short Vt[96][72];
  __shared__ short Ps[4][16][72];

  const int bid = blockIdx.x;
  const int bh = bid & 15;
  const int q0 = (bid >> 4) * 64;
  const int b_ = bh >> 3, h = bh & 7;
  const int tid = threadIdx.x;
  const int w = tid >> 6, lane = tid & 63;
  const int m16 = lane & 15, g4 = lane >> 4;

  const float sc2 = 0.10206207261596577f * 1.4426950408889634f;

  short8 qf[3];
  {
    const u16* qrow = qkv + ((size_t)(b_ * LSEQ) + q0 + w * 16 + m16) * 2304 + h * HDIM;
    #pragma unroll
    for (int c = 0; c < 3; ++c)
      qf[c] = *(const short8*)(qrow + c * 32 + g4 * 8);
  }

  float m_run[4], l_run[4];
  #pragma unroll
  for (int r = 0; r < 4; ++r) { m_run[r] = -INFINITY; l_run[r] = 0.f; }
  f32x4 oacc[6];
  #pragma unroll
  for (int ct = 0; ct < 6; ++ct) oacc[ct] = (f32x4)(0.f);

  const int kr = tid >> 2;
  const int cc = (tid & 3) * 24;

  for (int t = 0; t < LSEQ / 64; ++t) {
    const int k0 = t * 64;
    __syncthreads();
    {
      const u16* kp = qkv + ((size_t)(b_ * LSEQ) + k0 + kr) * 2304 + DMODEL + h * HDIM + cc;
      const u16* vp = kp + DMODEL;
      #pragma unroll
      for (int u = 0; u < 3; ++u) {
        short8 kv = *(const short8*)(kp + u * 8);
        *(short8*)&Ks[kr][cc + u * 8] = kv;
        short8 vv = *(const short8*)(vp + u * 8);
        #pragma unroll
        for (int e = 0; e < 8; ++e)
          Vt[cc + u * 8 + e][kr] = vv[e];
      }
    }
    __syncthreads();

    f32x4 sacc[4];
    #pragma unroll
    for (int kt = 0; kt < 4; ++kt) sacc[kt] = (f32x4)(0.f);
    #pragma unroll
    for (int c = 0; c < 3; ++c) {
      #pragma unroll
      for (int kt = 0; kt < 4; ++kt) {
        short8 bfrag = *(const short8*)&Ks[kt * 16 + m16][c * 32 + g4 * 8];
        sacc[kt] = __builtin_amdgcn_mfma_f32_16x16x32_bf16(qf[c], bfrag, sacc[kt], 0, 0, 0);
      }
    }

    #pragma unroll
    for (int r = 0; r < 4; ++r) {
      float s0 = sacc[0][r] * sc2, s1 = sacc[1][r] * sc2;
      float s2v = sacc[2][r] * sc2, s3 = sacc[3][r] * sc2;
      float mv = fmaxf(fmaxf(s0, s1), fmaxf(s2v, s3));
      mv = fmaxf(mv, __shfl_xor(mv, 1));
      mv = fmaxf(mv, __shfl_xor(mv, 2));
      mv = fmaxf(mv, __shfl_xor(mv, 4));
      mv = fmaxf(mv, __shfl_xor(mv, 8));
      float mnew = fmaxf(m_run[r], mv);
      float scale = exp2f(m_run[r] - mnew);
      float p0 = exp2f(s0 - mnew), p1 = exp2f(s1 - mnew);
      float p2 = exp2f(s2v - mnew), p3 = exp2f(s3 - mnew);
      short* pr = &Ps[w][g4 * 4 + r][m16];
      pr[0]  = f2bf(p0);
      pr[16] = f2bf(p1);
      pr[32] = f2bf(p2);
      pr[48] = f2bf(p3);
      float ps = p0 + p1 + p2 + p3;
      ps += __shfl_xor(ps, 1);
      ps += __shfl_xor(ps, 2);
      ps += __shfl_xor(ps, 4);
      ps += __shfl_xor(ps, 8);
      l_run[r] = l_run[r] * scale + ps;
      m_run[r] = mnew;
      #pragma unroll
      for (int ct = 0; ct < 6; ++ct) oacc[ct][r] *= scale;
    }

    #pragma unroll
    for (int kc = 0; kc < 2; ++kc) {
      short8 pa = *(const short8*)&Ps[w][m16][kc * 32 + g4 * 8];
      #pragma unroll
      for (int ct = 0; ct < 6; ++ct) {
        short8 vb = *(const short8*)&Vt[ct * 16 + m16][kc * 32 + g4 * 8];
        oacc[ct] = __builtin_amdgcn_mfma_f32_16x16x32_bf16(pa, vb, oacc[ct], 0, 0, 0);
      }
    }
  }

  #pragma unroll
  for (int r = 0; r < 4; ++r) {
    float inv = 1.f / l_run[r];
    u16* orow = o + ((size_t)(b_ * LSEQ) + q0 + w * 16 + g4 * 4 + r) * DMODEL + h * HDIM;
    #pragma unroll
    for (int ct = 0; ct < 6; ++ct)
      orow[ct * 16 + m16] = (u16)f2bf(oacc[ct][r] * inv);
  }
}

// ---------------------------------------------------------------------------
// GLCE convs (kernels 3/5/7, 3 in-ch per out-ch, exact gelu) -> bf16
// ---------------------------------------------------------------------------
__global__ __launch_bounds__(256) void glce_conv(
    const float* __restrict__ x,
    const float* __restrict__ w3, const float* __restrict__ b3,
    const float* __restrict__ w5, const float* __restrict__ b5,
    const float* __restrict__ w7, const float* __restrict__ b7,
    u16* __restrict__ loc)
{
  int idx = blockIdx.x * 256 + threadIdx.x;
  int c = idx % DMODEL;
  int bl = idx / DMODEL;
  int l = bl & 1023, b_ = bl >> 10;
  int cs = c >> 8, ch = c & 255;
  const float* wp; float bias; int kt, pad;
  if (cs == 0)      { wp = w3 + ch * 9;  bias = b3[ch]; kt = 3; pad = 1; }
  else if (cs == 1) { wp = w5 + ch * 15; bias = b5[ch]; kt = 5; pad = 2; }
  else              { wp = w7 + ch * 21; bias = b7[ch]; kt = 7; pad = 3; }
  float acc = bias;
  const float* xb = x + (size_t)(b_ * LSEQ) * DMODEL;
  for (int i = 0; i < 3; ++i) {
    int d = 3 * ch + i;
    for (int t = 0; t < kt; ++t) {
      int ls = l - pad + t;
      if (ls >= 0 && ls < LSEQ)
        acc = fmaf(xb[(size_t)ls * DMODEL + d], wp[i * kt + t], acc);
    }
  }
  loc[idx] = (u16)f2bf(0.5f * acc * (1.f + erff(acc * 0.7071067811865475f)));
}

// ---------------------------------------------------------------------------
// Mamba depthwise causal conv (K=4) + silu
// ---------------------------------------------------------------------------
__global__ __launch_bounds__(256) void mamba_conv_f32(
    const float* __restrict__ xiz, const float* __restrict__ cw,
    const float* __restrict__ cb, float* __restrict__ xc)
{
  int idx = blockIdx.x * 256 + threadIdx.x;
  int d = idx % DI_;
  int bl = idx / DI_;
  int l = bl & 1023, b_ = bl >> 10;
  const float* w = cw + d * 4;
  float acc = cb[d];
  #pragma unroll
  for (int t = 0; t < 4; ++t) {
    int ls = l - 3 + t;
    if (ls >= 0)
      acc = fmaf(xiz[((size_t)(b_ * LSEQ + ls)) * 3072 + d], w[t], acc);
  }
  xc[idx] = acc / (1.f + __expf(-acc));
}

// ---------------------------------------------------------------------------
// Chunked selective scan, 4 states per thread. CHUNK=64, NCHUNK=16.
// ---------------------------------------------------------------------------
__global__ __launch_bounds__(256) void mamba_scan_part(
    const float* __restrict__ dbc, const float* __restrict__ delta,
    const float* __restrict__ xc, const float* __restrict__ A_log,
    float* __restrict__ SS, float* __restrict__ PP)
{
  const int bc = blockIdx.x;
  const int b_ = bc / 384;
  const int rem = bc % 384;
  const int d0 = (rem >> 4) * 64;
  const int ck = rem & 15;
  const int tid = threadIdx.x;
  const int dl = tid >> 2, ng = tid & 3;
  const int d = d0 + dl;

  float4 a2;
  {
    float4 al = *(const float4*)&A_log[d * 16 + ng * 4];
    a2.x = -__expf(al.x) * 1.4426950408889634f;
    a2.y = -__expf(al.y) * 1.4426950408889634f;
    a2.z = -__expf(al.z) * 1.4426950408889634f;
    a2.w = -__expf(al.w) * 1.4426950408889634f;
  }

  __shared__ float sdel[32][64];
  __shared__ float sxc[32][64];
  __shared__ float sB[32][16];
  const size_t rowb = (size_t)b_ * LSEQ + ck * 64;

  float4 h = {0.f, 0.f, 0.f, 0.f};
  float sumd = 0.f;

  for (int half = 0; half < 2; ++half) {
    const int lbase = half * 32;
    __syncthreads();
    #pragma unroll
    for (int k = 0; k < 8; ++k) {
      int i = tid + k * 256;
      int lc = i >> 6, c = i & 63;
      size_t row = rowb + lbase + lc;
      sdel[lc][c] = delta[row * 1536 + d0 + c];
      sxc[lc][c]  = xc[row * 1536 + d0 + c];
    }
    #pragma unroll
    for (int k = 0; k < 2; ++k) {
      int i = tid + k * 256;
      int lc = i >> 4, n = i & 15;
      sB[lc][n] = dbc[(rowb + lbase + lc) * 80 + 48 + n];
    }
    __syncthreads();
    for (int lc = 0; lc < 32; ++lc) {
      float dlv = sdel[lc][dl];
      float xv  = sxc[lc][dl];
      float dx  = dlv * xv;
      float4 B4 = *(const float4*)&sB[lc][ng * 4];
      h.x = fmaf(exp2f(dlv * a2.x), h.x, dx * B4.x);
      h.y = fmaf(exp2f(dlv * a2.y), h.y, dx * B4.y);
      h.z = fmaf(exp2f(dlv * a2.z), h.z, dx * B4.z);
      h.w = fmaf(exp2f(dlv * a2.w), h.w, dx * B4.w);
      sumd += dlv;
    }
  }

  size_t idx = (((size_t)b_ * 1536 + d) * 16 + ck) * 16 + ng * 4;
  *(float4*)&SS[idx] = h;
  float4 pp;
  pp.x = exp2f(a2.x * sumd);
  pp.y = exp2f(a2.y * sumd);
  pp.z = exp2f(a2.z * sumd);
  pp.w = exp2f(a2.w * sumd);
  *(float4*)&PP[idx] = pp;
}

__global__ __launch_bounds__(256) void mamba_scan_comb(
    const float* __restrict__ SS, const float* __restrict__ PP,
    float* __restrict__ HI)
{
  int t = blockIdx.x * 256 + threadIdx.x;
  size_t base = (size_t)(t >> 4) * 256 + (t & 15);
  float run = 0.f;
  #pragma unroll
  for (int c = 0; c < 16; ++c) {
    size_t idx = base + c * 16;
    HI[idx] = run;
    run = fmaf(PP[idx], run, SS[idx]);
  }
}

__global__ __launch_bounds__(256) void mamba_scan_fin(
    const float* __restrict__ dbc, const float* __restrict__ delta,
    const float* __restrict__ xc, const float* __restrict__ xiz,
    const float* __restrict__ A_log, const float* __restrict__ Dp,
    const float* __restrict__ HI, u16* __restrict__ yg)
{
  const int bc = blockIdx.x;
  const int b_ = bc / 384;
  const int rem = bc % 384;
  const int d0 = (rem >> 4) * 64;
  const int ck = rem & 15;
  const int tid = threadIdx.x;
  const int dl = tid >> 2, ng = tid & 3;
  const int d = d0 + dl;

  float4 a2;
  {
    float4 al = *(const float4*)&A_log[d * 16 + ng * 4];
    a2.x = -__expf(al.x) * 1.4426950408889634f;
    a2.y = -__expf(al.y) * 1.4426950408889634f;
    a2.z = -__expf(al.z) * 1.4426950408889634f;
    a2.w = -__expf(al.w) * 1.4426950408889634f;
  }
  const float dv = Dp[d];

  __shared__ float sdel[32][64];
  __shared__ float sxc[32][64];
  __shared__ float sz[32][64];
  __shared__ float sB[32][16];
  __shared__ float sC[32][16];
  __shared__ float sy[32][64];
  const size_t rowb = (size_t)b_ * LSEQ + ck * 64;

  float4 h = *(const float4*)&HI[(((size_t)b_ * 1536 + d) * 16 + ck) * 16 + ng * 4];

  for (int half = 0; half < 2; ++half) {
    const int lbase = half * 32;
    __syncthreads();   // prior half's sy fully drained
    #pragma unroll
    for (int k = 0; k < 8; ++k) {
      int i = tid + k * 256;
      int lc = i >> 6, c = i & 63;
      size_t row = rowb + lbase + lc;
      sdel[lc][c] = delta[row * 1536 + d0 + c];
      sxc[lc][c]  = xc[row * 1536 + d0 + c];
      sz[lc][c]   = xiz[row * 3072 + 1536 + d0 + c];
    }
    #pragma unroll
    for (int k = 0; k < 2; ++k) {
      int i = tid + k * 256;
      int lc = i >> 4, n = i & 15;
      size_t row = rowb + lbase + lc;
      sB[lc][n] = dbc[row * 80 + 48 + n];
      sC[lc][n] = dbc[row * 80 + 64 + n];
    }
    __syncthreads();
    for (int lc = 0; lc < 32; ++lc) {
      float dlv = sdel[lc][dl];
      float xv  = sxc[lc][dl];
      float dx  = dlv * xv;
      float4 B4 = *(const float4*)&sB[lc][ng * 4];
      float4 C4 = *(const float4*)&sC[lc][ng * 4];
      h.x = fmaf(exp2f(dlv * a2.x), h.x, dx * B4.x);
      h.y = fmaf(exp2f(dlv * a2.y), h.y, dx * B4.y);
      h.z = fmaf(exp2f(dlv * a2.z), h.z, dx * B4.z);
      h.w = fmaf(exp2f(dlv * a2.w), h.w, dx * B4.w);
      float p = fmaf(h.x, C4.x, fmaf(h.y, C4.y, fmaf(h.z, C4.z, h.w * C4.w)));
      p += __shfl_xor(p, 1);
      p += __shfl_xor(p, 2);
      if (ng == 0) {
        float zv = sz[lc][dl];
        float y = p + xv * dv;
        sy[lc][dl] = y * (zv / (1.f + __expf(-zv)));
      }
    }
    __syncthreads();
    #pragma unroll
    for (int k = 0; k < 8; ++k) {
      int i = tid + k * 256;
      int lc = i >> 6, c = i & 63;
      yg[(rowb + lbase + lc) * 1536 + d0 + c] = (u16)f2bf(sy[lc][c]);
    }
  }
}

// ---------------------------------------------------------------------------
// LayerNorm over last dim (768): fp32-out and bf16-out variants
// ---------------------------------------------------------------------------
__global__ __launch_bounds__(256) void ln_f32(
    const float* __restrict__ in, const float* __restrict__ g,
    const float* __restrict__ b, float* __restrict__ out)
{
  int row = blockIdx.x * 4 + (threadIdx.x >> 6);
  int lane = threadIdx.x & 63;
  const float* xr = in + (size_t)row * DMODEL;
  float v[12];
  float s = 0.f, s2 = 0.f;
  #pragma unroll
  for (int i = 0; i < 12; ++i) {
    float t = xr[i * 64 + lane];
    v[i] = t; s += t; s2 = fmaf(t, t, s2);
  }
  #pragma unroll
  for (int off = 1; off < 64; off <<= 1) {
    s += __shfl_xor(s, off);
    s2 += __shfl_xor(s2, off);
  }
  float mean = s * (1.f / 768.f);
  float var = s2 * (1.f / 768.f) - mean * mean;
  float inv = rsqrtf(var + 1e-5f);
  float* orow = out + (size_t)row * DMODEL;
  #pragma unroll
  for (int i = 0; i < 12; ++i) {
    int c = i * 64 + lane;
    orow[c] = (v[i] - mean) * inv * g[c] + b[c];
  }
}

__global__ __launch_bounds__(256) void ln_bf16(
    const float* __restrict__ in, const float* __restrict__ g,
    const float* __restrict__ b, u16* __restrict__ out)
{
  int row = blockIdx.x * 4 + (threadIdx.x >> 6);
  int lane = threadIdx.x & 63;
  const float* xr = in + (size_t)row * DMODEL;
  float v[12];
  float s = 0.f, s2 = 0.f;
  #pragma unroll
  for (int i = 0; i < 12; ++i) {
    float t = xr[i * 64 + lane];
    v[i] = t; s += t; s2 = fmaf(t, t, s2);
  }
  #pragma unroll
  for (int off = 1; off < 64; off <<= 1) {
    s += __shfl_xor(s, off);
    s2 += __shfl_xor(s2, off);
  }
  float mean = s * (1.f / 768.f);
  float var = s2 * (1.f / 768.f) - mean * mean;
  float inv = rsqrtf(var + 1e-5f);
  u16* orow = out + (size_t)row * DMODEL;
  #pragma unroll
  for (int i = 0; i < 12; ++i) {
    int c = i * 64 + lane;
    orow[c] = (u16)f2bf((v[i] - mean) * inv * g[c] + b[c]);
  }
}

__global__ __launch_bounds__(256) void add3_f32(
    const float* __restrict__ a, const float* __restrict__ b,
    const float* __restrict__ c, float* __restrict__ o)
{
  int i = blockIdx.x * 256 + threadIdx.x;
  o[i] = a[i] + b[i] + c[i];
}

// ---------------------------------------------------------------------------
extern "C" void kernel_launch(void* const* d_in, const int* in_sizes, int n_in,
                              void* d_out, int out_size, void* d_ws, size_t ws_size,
                              hipStream_t stream)
{
  (void)in_sizes; (void)n_in; (void)out_size; (void)ws_size;
  const float* x         = (const float*)d_in[0];
  const float* qkv_w     = (const float*)d_in[1];
  const float* qkv_b     = (const float*)d_in[2];
  const float* att_out_w = (const float*)d_in[3];
  const float* att_out_b = (const float*)d_in[4];
  const float* conv3_w   = (const float*)d_in[5];
  const float* conv3_b   = (const float*)d_in[6];
  const float* conv5_w   = (const float*)d_in[7];
  const float* conv5_b   = (const float*)d_in[8];
  const float* conv7_w   = (const float*)d_in[9];
  const float* conv7_b   = (const float*)d_in[10];
  const float* gproj_w   = (const float*)d_in[11];
  const float* gproj_b   = (const float*)d_in[12];
  const float* lproj_w   = (const float*)d_in[13];
  const float* lproj_b   = (const float*)d_in[14];
  const float* fus_w     = (const float*)d_in[15];
  const float* fus_b     = (const float*)d_in[16];
  const float* glce_g    = (const float*)d_in[17];
  const float* glce_bb   = (const float*)d_in[18];
  const float* ssm_g     = (const float*)d_in[19];
  const float* ssm_bb    = (const float*)d_in[20];
  const float* in_w[2]   = {(const float*)d_in[21], (const float*)d_in[30]};
  const float* cw[2]     = {(const float*)d_in[22], (const float*)d_in[31]};
  const float* cb[2]     = {(const float*)d_in[23], (const float*)d_in[32]};
  const float* xp_w[2]   = {(const float*)d_in[24], (const float*)d_in[33]};
  const float* dt_w[2]   = {(const float*)d_in[25], (const float*)d_in[34]};
  const float* dt_b[2]   = {(const float*)d_in[26], (const float*)d_in[35]};
  const float* A_log[2]  = {(const float*)d_in[27], (const float*)d_in[36]};
  const float* Dp[2]     = {(const float*)d_in[28], (const float*)d_in[37]};
  const float* out_w[2]  = {(const float*)d_in[29], (const float*)d_in[38]};
  const float* ffn_g     = (const float*)d_in[39];
  const float* ffn_bb    = (const float*)d_in[40];
  const float* gate_w    = (const float*)d_in[41];
  const float* up_w      = (const float*)d_in[42];
  const float* down_w    = (const float*)d_in[43];

  float* ws = (float*)d_ws;
  size_t off = 0;
  const size_t M = 2048;
  auto take = [&](size_t n) { float* p = ws + off; off += n; return p; };
  auto takeb = [&](size_t n) { u16* p = (u16*)(ws + off); off += (n + 1) / 2; return p; };

  float* T1    = take(M * 768);
  float* X1    = take(M * 768);
  float* XIZ   = take(M * 3072);
  float* XC    = take(M * 1536);
  float* DBC   = take(M * 80);
  float* DELTA = take(M * 1536);
  float* YF    = take(M * 768);
  float* YB    = take(M * 768);
  float* X2    = take(M * 768);
  float* SS    = take(2 * 1536 * 16 * 16);
  float* PP    = take(2 * 1536 * 16 * 16);
  float* HI    = take(2 * 1536 * 16 * 16);
  float* PART  = take((size_t)XP_KSPLIT * M * 80);

  u16* QKVbf = takeb(M * 2304);
  u16* Xbf   = takeb(M * 768);
  u16* AObf  = takeb(M * 768);
  u16* AO2bf = takeb(M * 768);
  u16* GLbf  = takeb(M * 768);
  u16* LOCbf = takeb(M * 768);
  u16* XNbf  = takeb(M * 768);
  u16* YGbf  = takeb(M * 1536);
  u16* GUbf  = (u16*)XIZ;            // alias: XIZ fully consumed before FFN

  // bf16 weights
  u16* wQKV  = takeb(2304 * 768);
  u16* wAT   = takeb(768 * 768);
  u16* wGP   = takeb(384 * 768);
  u16* wLP   = takeb(384 * 768);
  u16* wFU   = takeb(768 * 768);
  u16* wIN[2]  = {takeb(3072 * 768), takeb(3072 * 768)};
  u16* wOUT[2] = {takeb(768 * 1536), takeb(768 * 1536)};
  u16* wGA   = takeb(3072 * 768);
  u16* wUP   = takeb(3072 * 768);
  u16* wDN   = takeb(768 * 3072);

  float* YFB[2] = {YF, YB};
  dim3 blk(256);

  // --- batched fp32 -> bf16 conversions (one launch) ---
  {
    CvtJobs j;
    const float* ss[NCVT] = {x, qkv_w, att_out_w, gproj_w, lproj_w, fus_w,
                             in_w[0], in_w[1], out_w[0], out_w[1],
                             gate_w, up_w, down_w};
    u16* dd[NCVT] = {Xbf, wQKV, wAT, wGP, wLP, wFU,
                     wIN[0], wIN[1], wOUT[0], wOUT[1], wGA, wUP, wDN};
    int nn[NCVT] = {2048 * 768, 2304 * 768, 768 * 768, 384 * 768, 384 * 768,
                    768 * 768, 3072 * 768, 3072 * 768, 768 * 1536, 768 * 1536,
                    3072 * 768, 3072 * 768, 768 * 3072};
    int total = 0;
    for (int e = 0; e < NCVT; ++e) {
      j.s[e] = ss[e]; j.d[e] = dd[e]; j.nblk[e] = nn[e] / 1024;
      total += j.nblk[e];
    }
    cvt_batch<<<dim3(total), blk, 0, stream>>>(j);
  }

  // --- GLCE branch ---
  gemm_mx<1><<<dim3(16 * 18), blk, 0, stream>>>(Xbf, 768, 0, wQKV, qkv_b, nullptr,
                                                QKVbf, 2304, 0, 0, 2304, 768, 0);
  attn_mfma<<<dim3(256), blk, 0, stream>>>(QKVbf, AObf);
  gemm_mx<1><<<dim3(16 * 6), blk, 0, stream>>>(AObf, 768, 0, wAT, att_out_b, nullptr,
                                               AO2bf, 768, 0, 0, 768, 768, 0);
  gemm_mx<1><<<dim3(16 * 3), blk, 0, stream>>>(AO2bf, 768, 0, wGP, gproj_b, nullptr,
                                               GLbf, 768, 0, 0, 384, 768, 0);
  glce_conv<<<dim3(M * 768 / 256), blk, 0, stream>>>(x, conv3_w, conv3_b, conv5_w,
                                                     conv5_b, conv7_w, conv7_b, LOCbf);
  gemm_mx<1><<<dim3(16 * 3), blk, 0, stream>>>(LOCbf, 768, 0, wLP, lproj_b, nullptr,
                                               GLbf, 768, 384, 0, 384, 768, 0);
  gemm_mx<0><<<dim3(16 * 6), blk, 0, stream>>>(GLbf, 768, 0, wFU, fus_b, x,
                                               T1, 768, 0, 0, 768, 768, 0);
  ln_f32<<<dim3(512), blk, 0, stream>>>(T1, glce_g, glce_bb, X1);

  // --- bidirectional mamba ---
  ln_bf16<<<dim3(512), blk, 0, stream>>>(X1, ssm_g, ssm_bb, XNbf);
  for (int dir = 0; dir < 2; ++dir) {
    int flip = dir;
    gemm_mx<0><<<dim3(16 * 24), blk, 0, stream>>>(XNbf, 768, flip, wIN[dir], nullptr, nullptr,
                                                  XIZ, 3072, 0, 0, 3072, 768, 0);
    mamba_conv_f32<<<dim3(M * 1536 / 256), blk, 0, stream>>>(XIZ, cw[dir], cb[dir], XC);
    xp_part<<<dim3(32, XP_KSPLIT), blk, 0, stream>>>(XC, xp_w[dir], PART);
    xp_reduce<<<dim3(M * 80 / 256), blk, 0, stream>>>(PART, DBC);
    gemm_f32<<<dim3(24, 32), blk, 0, stream>>>(DBC, 80, 0, dt_w[dir], dt_b[dir], nullptr,
                                               DELTA, 1536, 0, 0, 1536, 48, 1, 0);
    mamba_scan_part<<<dim3(768), blk, 0, stream>>>(DBC, DELTA, XC, A_log[dir], SS, PP);
    mamba_scan_comb<<<dim3(192), blk, 0, stream>>>(SS, PP, HI);
    mamba_scan_fin<<<dim3(768), blk, 0, stream>>>(DBC, DELTA, XC, XIZ, A_log[dir],
                                                  Dp[dir], HI, YGbf);
    gemm_mx<0><<<dim3(16 * 6), blk, 0, stream>>>(YGbf, 1536, 0, wOUT[dir], nullptr, nullptr,
                                                 YFB[dir], 768, 0, flip, 768, 1536, 0);
  }
  add3_f32<<<dim3(M * 768 / 256), blk, 0, stream>>>(X1, YF, YB, X2);

  // --- FFN ---
  ln_bf16<<<dim3(512), blk, 0, stream>>>(X2, ffn_g, ffn_bb, XNbf);
  gemm_mx<1><<<dim3(16 * 24), blk, 0, stream>>>(XNbf, 768, 0, wGA, nullptr, nullptr,
                                                GUbf, 3072, 0, 0, 3072, 768, 2);
  gemm_mx<2><<<dim3(16 * 24), blk, 0, stream>>>(XNbf, 768, 0, wUP, nullptr, nullptr,
                                                GUbf, 3072, 0, 0, 3072, 768, 0);
  gemm_mx<0><<<dim3(16 * 6), blk, 0, stream>>>(GUbf, 3072, 0, wDN, nullptr, X2,
                                               (float*)d_out, 768, 0, 0, 768, 3072, 0);
}